// Round 10
// baseline (844.811 us; speedup 1.0000x reference)
//
#include <hip/hip_runtime.h>
#include <hip/hip_bf16.h>
#include <math.h>

// Problem dims
#define SDIM 256
#define HDIM 768
#define EDIM 1536
#define NDIM 16
#define KCONV 4
#define RDIM 48
#define NLAYER 2
#define LSEQ 1024

#define NCHUNK 128
#define CHLEN (LSEQ / NCHUNK)   // 8
#define CPG (NCHUNK / 4)        // 32 chunks per prefix group
#define XSPLIT 8
#define XKCH (EDIM / XSPLIT)    // 192

// MEASUREMENT ROUND: layer-0 instances of the 5 unattributed kernels run their
// (idempotent) bodies REPS_MEAS times so they rise above the 43us harness fills
// into the top-5 counter table. dur_us is sacrificial this round.
#define REPS_MEAS 8

typedef __hip_bfloat16 bf16;
typedef __attribute__((ext_vector_type(8))) short short8;
typedef __attribute__((ext_vector_type(4))) float f32x4;

__device__ __forceinline__ float softplusf(float x) {
    return (x > 20.f) ? x : log1pf(expf(x));
}
__device__ __forceinline__ float siluf(float x) {
    return x / (1.f + expf(-x));
}

// stage 8 elements into LDS as bf16 (bf16 source: raw copy; fp32 source: convert)
__device__ __forceinline__ void ld8(short* d, const bf16* s) {
    *(uint4*)d = *(const uint4*)s;
}
__device__ __forceinline__ void ld8(short* d, const float* s) {
    float4 a = *(const float4*)s;
    float4 b = *(const float4*)(s + 4);
    bf16 t[8] = {(bf16)a.x, (bf16)a.y, (bf16)a.z, (bf16)a.w,
                 (bf16)b.x, (bf16)b.y, (bf16)b.z, (bf16)b.w};
    *(uint4*)d = *(const uint4*)t;
}

// ---------------- MFMA bf16 GEMM 64x64 tile, split-K, fp32 partials (emb, out_proj) ----
template <typename AT>
__global__ __launch_bounds__(256) void k_gemm_sk(const AT* __restrict__ A, int lda,
                                                 const float* __restrict__ W, int ldw,
                                                 const float* __restrict__ bias,
                                                 float* __restrict__ part,
                                                 int N, int Kh, int useBias, int reps)
{
    __shared__ __align__(16) short As[64][72];
    __shared__ __align__(16) short Ws[64][72];

    const int tid  = threadIdx.x;
    const int lane = tid & 63, wid = tid >> 6;
    const int wm = wid >> 1, wn = wid & 1;
    const int row0 = blockIdx.y * 64, col0 = blockIdx.x * 64;
    const int quad = lane >> 4, l16 = lane & 15;
    const int kbase = blockIdx.z * Kh;

    for (int rp = 0; rp < reps; rp++) {
    f32x4 acc[2][2] = {};
    for (int k0 = 0; k0 < Kh; k0 += 64) {
        #pragma unroll
        for (int i = 0; i < 2; i++) {
            int id = tid + i * 256;
            int r = id >> 3, g = id & 7;
            ld8(&As[r][g * 8], A + (size_t)(row0 + r) * lda + kbase + k0 + g * 8);
            ld8(&Ws[r][g * 8], W + (size_t)(col0 + r) * ldw + kbase + k0 + g * 8);
        }
        __syncthreads();
        #pragma unroll
        for (int ks = 0; ks < 64; ks += 32) {
            short8 af[2], bfr[2];
            #pragma unroll
            for (int i = 0; i < 2; i++) af[i] = *(const short8*)&As[wm * 32 + i * 16 + l16][ks + quad * 8];
            #pragma unroll
            for (int j = 0; j < 2; j++) bfr[j] = *(const short8*)&Ws[wn * 32 + j * 16 + l16][ks + quad * 8];
            #pragma unroll
            for (int i = 0; i < 2; i++)
                #pragma unroll
                for (int j = 0; j < 2; j++)
                    acc[i][j] = __builtin_amdgcn_mfma_f32_16x16x32_bf16(af[i], bfr[j], acc[i][j], 0, 0, 0);
        }
        __syncthreads();
    }
    float* pdst = part + (size_t)blockIdx.z * LSEQ * N;
    #pragma unroll
    for (int i = 0; i < 2; i++) {
        #pragma unroll
        for (int j = 0; j < 2; j++) {
            int gn = col0 + wn * 32 + j * 16 + l16;
            int gm0 = row0 + wm * 32 + i * 16 + quad * 4;
            #pragma unroll
            for (int r = 0; r < 4; r++) {
                float v = acc[i][j][r];
                if (useBias && blockIdx.z == 0) v += bias[gn];
                pdst[(size_t)(gm0 + r) * N + gn] = v;
            }
        }
    }
    }
}

// ---------------- in_proj GEMM: no split-K, writes bf16 xz directly ----------------
__global__ __launch_bounds__(256) void k_gemm_skb(const bf16* __restrict__ A, int lda,
                                                  const float* __restrict__ W, int ldw,
                                                  bf16* __restrict__ outp,
                                                  int N, int Kh, int reps)
{
    __shared__ __align__(16) short As[64][72];
    __shared__ __align__(16) short Ws[64][72];

    const int tid  = threadIdx.x;
    const int lane = tid & 63, wid = tid >> 6;
    const int wm = wid >> 1, wn = wid & 1;
    const int row0 = blockIdx.y * 64, col0 = blockIdx.x * 64;
    const int quad = lane >> 4, l16 = lane & 15;

    for (int rp = 0; rp < reps; rp++) {
    f32x4 acc[2][2] = {};
    for (int k0 = 0; k0 < Kh; k0 += 64) {
        #pragma unroll
        for (int i = 0; i < 2; i++) {
            int id = tid + i * 256;
            int r = id >> 3, g = id & 7;
            ld8(&As[r][g * 8], A + (size_t)(row0 + r) * lda + k0 + g * 8);
            ld8(&Ws[r][g * 8], W + (size_t)(col0 + r) * ldw + k0 + g * 8);
        }
        __syncthreads();
        #pragma unroll
        for (int ks = 0; ks < 64; ks += 32) {
            short8 af[2], bfr[2];
            #pragma unroll
            for (int i = 0; i < 2; i++) af[i] = *(const short8*)&As[wm * 32 + i * 16 + l16][ks + quad * 8];
            #pragma unroll
            for (int j = 0; j < 2; j++) bfr[j] = *(const short8*)&Ws[wn * 32 + j * 16 + l16][ks + quad * 8];
            #pragma unroll
            for (int i = 0; i < 2; i++)
                #pragma unroll
                for (int j = 0; j < 2; j++)
                    acc[i][j] = __builtin_amdgcn_mfma_f32_16x16x32_bf16(af[i], bfr[j], acc[i][j], 0, 0, 0);
        }
        __syncthreads();
    }
    #pragma unroll
    for (int i = 0; i < 2; i++) {
        #pragma unroll
        for (int j = 0; j < 2; j++) {
            int gn = col0 + wn * 32 + j * 16 + l16;
            int gm0 = row0 + wm * 32 + i * 16 + quad * 4;
            #pragma unroll
            for (int r = 0; r < 4; r++)
                outp[(size_t)(gm0 + r) * N + gn] = (bf16)acc[i][j][r];
        }
    }
    }
}

// ---------------- head GEMM: A = sum of two fp32 partials, W fp32 ----------------
__global__ __launch_bounds__(256) void k_gemm_h(const float* __restrict__ A0,
                                                const float* __restrict__ A1, int lda,
                                                const float* __restrict__ W, int ldw,
                                                const float* __restrict__ bias,
                                                float* __restrict__ out, int N, int Kd)
{
    __shared__ __align__(16) short As[64][72];
    __shared__ __align__(16) short Ws[64][72];

    const int tid  = threadIdx.x;
    const int lane = tid & 63, wid = tid >> 6;
    const int wm = wid >> 1, wn = wid & 1;
    const int row0 = blockIdx.y * 64, col0 = blockIdx.x * 64;
    const int quad = lane >> 4, l16 = lane & 15;

    f32x4 acc[2][2] = {};
    for (int k0 = 0; k0 < Kd; k0 += 64) {
        #pragma unroll
        for (int i = 0; i < 2; i++) {
            int id = tid + i * 256;
            int r = id >> 3, g = id & 7;
            size_t base = (size_t)(row0 + r) * lda + k0 + g * 8;
            float4 a0 = *(const float4*)(A0 + base);
            float4 a1 = *(const float4*)(A0 + base + 4);
            float4 b0 = *(const float4*)(A1 + base);
            float4 b1 = *(const float4*)(A1 + base + 4);
            bf16 tmp[8] = {(bf16)(a0.x + b0.x), (bf16)(a0.y + b0.y),
                           (bf16)(a0.z + b0.z), (bf16)(a0.w + b0.w),
                           (bf16)(a1.x + b1.x), (bf16)(a1.y + b1.y),
                           (bf16)(a1.z + b1.z), (bf16)(a1.w + b1.w)};
            *(uint4*)&As[r][g * 8] = *(const uint4*)tmp;
            ld8(&Ws[r][g * 8], W + (size_t)(col0 + r) * ldw + k0 + g * 8);
        }
        __syncthreads();
        #pragma unroll
        for (int ks = 0; ks < 64; ks += 32) {
            short8 af[2], bfr[2];
            #pragma unroll
            for (int i = 0; i < 2; i++) af[i] = *(const short8*)&As[wm * 32 + i * 16 + l16][ks + quad * 8];
            #pragma unroll
            for (int j = 0; j < 2; j++) bfr[j] = *(const short8*)&Ws[wn * 32 + j * 16 + l16][ks + quad * 8];
            #pragma unroll
            for (int i = 0; i < 2; i++)
                #pragma unroll
                for (int j = 0; j < 2; j++)
                    acc[i][j] = __builtin_amdgcn_mfma_f32_16x16x32_bf16(af[i], bfr[j], acc[i][j], 0, 0, 0);
        }
        __syncthreads();
    }
    #pragma unroll
    for (int i = 0; i < 2; i++) {
        #pragma unroll
        for (int j = 0; j < 2; j++) {
            int gn = col0 + wn * 32 + j * 16 + l16;
            int gm0 = row0 + wm * 32 + i * 16 + quad * 4;
            #pragma unroll
            for (int r = 0; r < 4; r++)
                out[(size_t)(gm0 + r) * N + gn] = acc[i][j][r] + bias[gn];
        }
    }
}

// ---------------- xproj GEMM with fused causal-conv+silu A-staging ----------------
__global__ __launch_bounds__(256) void k_xproj_conv(
    const bf16* __restrict__ xz,
    const float* __restrict__ W,     // x_proj fp32 [80][EDIM]
    const float* __restrict__ cw,    // [EDIM][4]
    const float* __restrict__ cb,    // [EDIM]
    float* __restrict__ part,
    bf16* __restrict__ ub, int reps)
{
    __shared__ __align__(16) short As[64][72];
    __shared__ __align__(16) short Ws[64][72];
    __shared__ __align__(16) bf16 Xr[67][64];

    const int tid  = threadIdx.x;
    const int lane = tid & 63, wid = tid >> 6;
    const int wm = wid >> 1, wn = wid & 1;
    const int row0 = blockIdx.y * 64, col0 = blockIdx.x * 64;
    const int quad = lane >> 4, l16 = lane & 15;
    const int kbase = blockIdx.z * XKCH;

    for (int rp = 0; rp < reps; rp++) {
    f32x4 acc[2][2] = {};
    for (int k0 = 0; k0 < XKCH; k0 += 64) {
        const int ecol = kbase + k0;
        for (int idx = tid; idx < 67 * 8; idx += 256) {
            int r = idx >> 3, g = idx & 7;
            int gr = row0 - 3 + r;
            uint4 v = {0, 0, 0, 0};
            if (gr >= 0) v = *(const uint4*)(xz + (size_t)gr * (2 * EDIM) + ecol + g * 8);
            *(uint4*)&Xr[r][g * 8] = v;
        }
        #pragma unroll
        for (int i = 0; i < 2; i++) {
            int id = tid + i * 256;
            int r = id >> 3, g = id & 7;
            if (col0 + r < 80) {
                ld8(&Ws[r][g * 8], W + (size_t)(col0 + r) * EDIM + ecol + g * 8);
            } else {
                uint4 z = {0, 0, 0, 0};
                *(uint4*)&Ws[r][g * 8] = z;
            }
        }
        __syncthreads();
        {
            const int e = tid & 63;
            const int rb = (tid >> 6) * 16;
            const float cw0 = cw[(ecol + e) * 4 + 0];
            const float cw1 = cw[(ecol + e) * 4 + 1];
            const float cw2 = cw[(ecol + e) * 4 + 2];
            const float cw3 = cw[(ecol + e) * 4 + 3];
            const float cbv = cb[ecol + e];
            #pragma unroll
            for (int j = 0; j < 16; j++) {
                int r = rb + j;
                float s = cbv
                        + cw0 * (float)Xr[r + 0][e]
                        + cw1 * (float)Xr[r + 1][e]
                        + cw2 * (float)Xr[r + 2][e]
                        + cw3 * (float)Xr[r + 3][e];
                bf16 h = (bf16)siluf(s);
                As[r][e] = *reinterpret_cast<short*>(&h);
            }
        }
        __syncthreads();
        if (blockIdx.x == 0) {
            for (int idx = tid; idx < 64 * 8; idx += 256) {
                int r = idx >> 3, g = idx & 7;
                *(uint4*)(ub + (size_t)(row0 + r) * EDIM + ecol + g * 8) = *(const uint4*)&As[r][g * 8];
            }
        }
        #pragma unroll
        for (int ks = 0; ks < 64; ks += 32) {
            short8 af[2], bfr[2];
            #pragma unroll
            for (int i = 0; i < 2; i++) af[i] = *(const short8*)&As[wm * 32 + i * 16 + l16][ks + quad * 8];
            #pragma unroll
            for (int j = 0; j < 2; j++) bfr[j] = *(const short8*)&Ws[wn * 32 + j * 16 + l16][ks + quad * 8];
            #pragma unroll
            for (int i = 0; i < 2; i++)
                #pragma unroll
                for (int j = 0; j < 2; j++)
                    acc[i][j] = __builtin_amdgcn_mfma_f32_16x16x32_bf16(af[i], bfr[j], acc[i][j], 0, 0, 0);
        }
        __syncthreads();
    }

    float* pdst = part + (size_t)blockIdx.z * (LSEQ * 80);
    #pragma unroll
    for (int i = 0; i < 2; i++) {
        #pragma unroll
        for (int j = 0; j < 2; j++) {
            int gn = col0 + wn * 32 + j * 16 + l16;
            int gm0 = row0 + wm * 32 + i * 16 + quad * 4;
            if (gn < 80) {
                #pragma unroll
                for (int r = 0; r < 4; r++)
                    pdst[(size_t)(gm0 + r) * 80 + gn] = acc[i][j][r];
            }
        }
    }
    }
}

// ---------------- split-K reduce: part[8][LSEQ][80] -> dbc[LSEQ][80] ----------------
__global__ __launch_bounds__(256) void k_red8(const float* __restrict__ part,
                                              float* __restrict__ dbc)
{
    const int i = (blockIdx.x * 256 + threadIdx.x) * 4;
    float4 s = *(const float4*)(part + i);
    #pragma unroll
    for (int p = 1; p < XSPLIT; p++) {
        float4 v = *(const float4*)(part + (size_t)p * (LSEQ * 80) + i);
        s.x += v.x; s.y += v.y; s.z += v.z; s.w += v.w;
    }
    *(float4*)(dbc + i) = s;
}

// ---------------- residual + rmsnorm ----------------
__global__ __launch_bounds__(256) void k_rms(const float* __restrict__ h0,
                                             const float* __restrict__ h1,
                                             float* __restrict__ res,
                                             bf16* __restrict__ hnb, const float* __restrict__ w,
                                             int first)
{
    __shared__ float red[4];
    __shared__ float tot;
    const int tid = threadIdx.x;
    const int t = blockIdx.x;
    float v[3]; float ss = 0.f;
    #pragma unroll
    for (int r = 0; r < 3; r++) {
        int j = tid + r * 256;
        float xv = h0[(size_t)t * HDIM + j] + h1[(size_t)t * HDIM + j];
        if (!first) xv += res[(size_t)t * HDIM + j];
        v[r] = xv;
        res[(size_t)t * HDIM + j] = xv;
        ss += xv * xv;
    }
    #pragma unroll
    for (int m = 32; m >= 1; m >>= 1) ss += __shfl_down(ss, m);
    int wid = tid >> 6;
    if ((tid & 63) == 0) red[wid] = ss;
    __syncthreads();
    if (tid == 0) tot = red[0] + red[1] + red[2] + red[3];
    __syncthreads();
    float scale = rsqrtf(tot / (float)HDIM + 1e-5f);
    #pragma unroll
    for (int r = 0; r < 3; r++) {
        int j = tid + r * 256;
        hnb[(size_t)t * HDIM + j] = (bf16)(v[r] * scale * w[j]);
    }
}

// ---------------- shared helper: per-block dt/B/C tile from reduced dbc ----------
__device__ __forceinline__ void dt_tile(
    const float* __restrict__ dbc, const float* __restrict__ dtw,
    const float* __restrict__ dtbb,
    float (*A_red)[48], float (*BC)[32], float (*dtL)[256],
    int t0, int e, int tid)
{
    for (int idx = tid; idx < CHLEN * 80; idx += 256) {
        int tt = idx / 80, k = idx - tt * 80;
        float v = dbc[(size_t)(t0 + tt) * 80 + k];
        if (k < RDIM) A_red[tt][k] = v; else BC[tt][k - RDIM] = v;
    }
    __syncthreads();
    const float* we = dtw + (size_t)e * RDIM;
    const float bb = dtbb[e];
    float acc[CHLEN] = {};
    #pragma unroll 3
    for (int k = 0; k < RDIM; k += 4) {
        float4 w4 = *(const float4*)(we + k);
        #pragma unroll
        for (int j = 0; j < CHLEN; j++) {
            float4 a4 = *(const float4*)&A_red[j][k];
            acc[j] += a4.x * w4.x + a4.y * w4.y + a4.z * w4.z + a4.w * w4.w;
        }
    }
    #pragma unroll
    for (int j = 0; j < CHLEN; j++)
        dtL[j][tid] = softplusf(acc[j] + bb);
}

// ---------------- scan1: dt-GEMM + per-chunk local scan ----------------
__global__ __launch_bounds__(256) void k_scan1d(
    const float* __restrict__ dbc, const float* __restrict__ dtw,
    const float* __restrict__ dtbb,
    const bf16*  __restrict__ ub,
    const float* __restrict__ a_log,
    float* __restrict__ chunkS, float* __restrict__ sumdt, int reps)
{
    __shared__ __align__(16) float A_red[CHLEN][48];
    __shared__ __align__(16) float BC[CHLEN][32];
    __shared__ __align__(16) float dtL[CHLEN][256];
    const int tid = threadIdx.x;
    const int ex = blockIdx.x % 6, c = blockIdx.x / 6;
    const int e = ex * 256 + tid;
    const int t0 = c * CHLEN;

    for (int rp = 0; rp < reps; rp++) {
    __syncthreads();
    dt_tile(dbc, dtw, dtbb, A_red, BC, dtL, t0, e, tid);

    float u8[CHLEN];
    #pragma unroll
    for (int tt = 0; tt < CHLEN; tt++)
        u8[tt] = (float)ub[(size_t)(t0 + tt) * EDIM + e];

    float A[16];
    #pragma unroll
    for (int q = 0; q < 4; q++) {
        float4 a4 = *(const float4*)(a_log + (size_t)e * NDIM + q * 4);
        A[q*4+0] = -__expf(a4.x); A[q*4+1] = -__expf(a4.y);
        A[q*4+2] = -__expf(a4.z); A[q*4+3] = -__expf(a4.w);
    }
    float s[16] = {};
    float sd = 0.f;
    #pragma unroll
    for (int tt = 0; tt < CHLEN; tt++) {
        float dtv = dtL[tt][tid];
        float dtu = dtv * u8[tt];
        sd += dtv;
        #pragma unroll
        for (int n = 0; n < 16; n++) s[n] = s[n] * __expf(dtv * A[n]) + dtu * BC[tt][n];
    }
    float* cs = chunkS + ((size_t)c * EDIM + e) * NDIM;
    #pragma unroll
    for (int q = 0; q < 4; q++)
        *(float4*)(cs + q * 4) = make_float4(s[q*4+0], s[q*4+1], s[q*4+2], s[q*4+3]);
    sumdt[(size_t)c * EDIM + e] = sd;
    }
}

// ---------------- scan2: two-level affine prefix over chunks -> sInit ----------------
__global__ __launch_bounds__(256) void k_scan2p(
    const float* __restrict__ chunkS, const float* __restrict__ sumdt,
    const float* __restrict__ a_log, float* __restrict__ sInit)
{
    __shared__ float sP[256];
    __shared__ float sX[256];
    const int tid = threadIdx.x;
    const int pl = tid & 63, q = tid >> 6;
    const int p = blockIdx.x * 64 + pl;   // pair index = e*16+n
    const int pe = p >> 4;
    const float Aen = -__expf(a_log[p]);
    float P[CPG], X[CPG];
    float Pc = 1.f, Xc = 0.f;
    #pragma unroll
    for (int j = 0; j < CPG; j++) {
        int cc = q * CPG + j;
        float Pj = __expf(Aen * sumdt[(size_t)cc * EDIM + pe]);
        float Xj = chunkS[(size_t)cc * (EDIM * NDIM) + p];
        P[j] = Pj; X[j] = Xj;
        Xc = Pj * Xc + Xj;
        Pc *= Pj;
    }
    sP[q * 64 + pl] = Pc;
    sX[q * 64 + pl] = Xc;
    __syncthreads();
    float s = 0.f;
    for (int g = 0; g < q; g++) s = sP[g * 64 + pl] * s + sX[g * 64 + pl];
    #pragma unroll
    for (int j = 0; j < CPG; j++) {
        int cc = q * CPG + j;
        sInit[(size_t)cc * (EDIM * NDIM) + p] = s;
        s = P[j] * s + X[j];
    }
}

// ---------------- scan3: dt-GEMM + final scan with carry + y/z gating ----------
__global__ __launch_bounds__(256) void k_scan3d(
    const float* __restrict__ dbc, const float* __restrict__ dtw,
    const float* __restrict__ dtbb,
    const bf16*  __restrict__ ub,
    const bf16*  __restrict__ xz,
    const float* __restrict__ a_log,
    const float* __restrict__ Dp,
    const float* __restrict__ sInit,
    bf16* __restrict__ yzb, int reps)
{
    __shared__ __align__(16) float A_red[CHLEN][48];
    __shared__ __align__(16) float BC[CHLEN][32];
    __shared__ __align__(16) float dtL[CHLEN][256];
    const int tid = threadIdx.x;
    const int ex = blockIdx.x % 6, c = blockIdx.x / 6;
    const int e = ex * 256 + tid;
    const int t0 = c * CHLEN;

    for (int rp = 0; rp < reps; rp++) {
    __syncthreads();
    dt_tile(dbc, dtw, dtbb, A_red, BC, dtL, t0, e, tid);

    float u8[CHLEN], z8[CHLEN];
    #pragma unroll
    for (int tt = 0; tt < CHLEN; tt++) {
        u8[tt] = (float)ub[(size_t)(t0 + tt) * EDIM + e];
        z8[tt] = (float)xz[(size_t)(t0 + tt) * (2 * EDIM) + EDIM + e];
    }

    float A[16];
    #pragma unroll
    for (int q = 0; q < 4; q++) {
        float4 a4 = *(const float4*)(a_log + (size_t)e * NDIM + q * 4);
        A[q*4+0] = -__expf(a4.x); A[q*4+1] = -__expf(a4.y);
        A[q*4+2] = -__expf(a4.z); A[q*4+3] = -__expf(a4.w);
    }
    const float dv = Dp[e];
    float s[16];
    const float* si = sInit + ((size_t)c * EDIM + e) * NDIM;
    #pragma unroll
    for (int q = 0; q < 4; q++) {
        float4 s4 = *(const float4*)(si + q * 4);
        s[q*4+0] = s4.x; s[q*4+1] = s4.y; s[q*4+2] = s4.z; s[q*4+3] = s4.w;
    }
    #pragma unroll
    for (int tt = 0; tt < CHLEN; tt++) {
        float dtv = dtL[tt][tid];
        float uv  = u8[tt];
        float dtu = dtv * uv;
        float y = 0.f;
        #pragma unroll
        for (int n = 0; n < 16; n++) {
            s[n] = s[n] * __expf(dtv * A[n]) + dtu * BC[tt][n];
            y += s[n] * BC[tt][16 + n];
        }
        y += uv * dv;
        yzb[(size_t)(t0 + tt) * EDIM + e] = (bf16)(y * siluf(z8[tt]));
    }
    }
}

extern "C" void kernel_launch(void* const* d_in, const int* in_sizes, int n_in,
                              void* d_out, int out_size, void* d_ws, size_t ws_size,
                              hipStream_t stream)
{
    const float* x        = (const float*)d_in[0];
    const float* emb_w    = (const float*)d_in[1];
    const float* emb_b    = (const float*)d_in[2];
    const float* norm_w   = (const float*)d_in[3];
    const float* in_proj  = (const float*)d_in[4];
    const float* conv_w   = (const float*)d_in[5];
    const float* conv_b   = (const float*)d_in[6];
    const float* x_proj   = (const float*)d_in[7];
    const float* dt_w     = (const float*)d_in[8];
    const float* dt_b     = (const float*)d_in[9];
    const float* A_log    = (const float*)d_in[10];
    const float* Dp       = (const float*)d_in[11];
    const float* out_proj = (const float*)d_in[12];
    const float* head_w   = (const float*)d_in[13];
    const float* head_b   = (const float*)d_in[14];
    float* out = (float*)d_out;

    float* ws = (float*)d_ws;
    size_t off = 0;
    float* hpart  = ws + off; off += (size_t)2 * LSEQ * HDIM;
    float* res    = ws + off; off += (size_t)LSEQ * HDIM;
    float* part   = ws + off; off += (size_t)XSPLIT * LSEQ * 80;
    float* dbc    = ws + off; off += (size_t)LSEQ * 80;
    float* chunkS = ws + off; off += (size_t)NCHUNK * EDIM * NDIM;
    float* sumdt  = ws + off; off += (size_t)NCHUNK * EDIM;
    float* sInit  = ws + off; off += (size_t)NCHUNK * EDIM * NDIM;
    bf16* xz      = (bf16*)(ws + off); off += (size_t)LSEQ * 2 * EDIM / 2;
    bf16* hnb     = (bf16*)(ws + off); off += (size_t)LSEQ * HDIM / 2;
    bf16* yzb     = (bf16*)(ws + off); off += (size_t)LSEQ * EDIM / 2;
    bf16* ub      = (bf16*)(ws + off); off += (size_t)LSEQ * EDIM / 2;

    // embed: split-K=2 (Kh=128) -> hpart[2]
    k_gemm_sk<float><<<dim3(12, 16, 2), 256, 0, stream>>>(x, SDIM, emb_w, SDIM, emb_b,
                                                          hpart, HDIM, SDIM / 2, 1, 1);

    for (int l = 0; l < NLAYER; l++) {
        const float* inw  = in_proj  + (size_t)l * 2 * EDIM * HDIM;
        const float* outw = out_proj + (size_t)l * HDIM * EDIM;
        const float* xwl  = x_proj   + (size_t)l * 80 * EDIM;
        const float* cw   = conv_w   + (size_t)l * EDIM * KCONV;
        const float* cb   = conv_b   + (size_t)l * EDIM;
        const float* dtw  = dt_w     + (size_t)l * EDIM * RDIM;
        const float* dtbb = dt_b     + (size_t)l * EDIM;
        const float* al   = A_log    + (size_t)l * EDIM * NDIM;
        const float* Dpl  = Dp       + (size_t)l * EDIM;
        const int R = (l == 0) ? REPS_MEAS : 1;   // measurement reps on layer 0 only

        k_rms<<<LSEQ, 256, 0, stream>>>(hpart, hpart + (size_t)LSEQ * HDIM, res,
                                        hnb, norm_w + (size_t)l * HDIM, l == 0);
        k_gemm_skb<<<dim3(48, 16, 1), 256, 0, stream>>>(hnb, HDIM, inw, HDIM,
                                                        xz, 2 * EDIM, HDIM, R);
        k_xproj_conv<<<dim3(2, 16, XSPLIT), 256, 0, stream>>>(xz, xwl, cw, cb, part, ub, R);
        k_red8<<<LSEQ * 80 / 1024, 256, 0, stream>>>(part, dbc);
        k_scan1d<<<6 * NCHUNK, 256, 0, stream>>>(dbc, dtw, dtbb, ub, al, chunkS, sumdt, R);
        k_scan2p<<<EDIM * NDIM / 64, 256, 0, stream>>>(chunkS, sumdt, al, sInit);
        k_scan3d<<<6 * NCHUNK, 256, 0, stream>>>(dbc, dtw, dtbb, ub, xz, al, Dpl,
                                                 sInit, yzb, R);
        k_gemm_sk<bf16><<<dim3(12, 16, 2), 256, 0, stream>>>(yzb, EDIM, outw, EDIM, nullptr,
                                                             hpart, HDIM, EDIM / 2, 0, R);
    }

    // head: A = hpart0 + hpart1 (fp32), W fp32 converted in staging
    k_gemm_h<<<dim3(4, 16), 256, 0, stream>>>(hpart, hpart + (size_t)LSEQ * HDIM, HDIM,
                                              head_w, HDIM, head_b, out, SDIM, HDIM);
}

// Round 12
// 342.472 us; speedup vs baseline: 2.4668x; 2.4668x over previous
//
#include <hip/hip_runtime.h>
#include <hip/hip_bf16.h>
#include <math.h>

// Problem dims
#define SDIM 256
#define HDIM 768
#define EDIM 1536
#define NDIM 16
#define KCONV 4
#define RDIM 48
#define NLAYER 2
#define LSEQ 1024

#define NCHUNK 128
#define CHLEN (LSEQ / NCHUNK)   // 8
#define CPG (NCHUNK / 4)        // 32 chunks per prefix group
#define XSPLIT 8
#define XKCH (EDIM / XSPLIT)    // 192

typedef __hip_bfloat16 bf16;
typedef __attribute__((ext_vector_type(8))) short short8;
typedef __attribute__((ext_vector_type(4))) float f32x4;

__device__ __forceinline__ float softplusf(float x) {
    return (x > 20.f) ? x : log1pf(expf(x));
}
__device__ __forceinline__ float siluf(float x) {
    return x / (1.f + expf(-x));
}

// stage 8 elements into LDS as bf16 (bf16 source: raw copy; fp32 source: convert)
__device__ __forceinline__ void ld8(short* d, const bf16* s) {
    *(uint4*)d = *(const uint4*)s;
}
__device__ __forceinline__ void ld8(short* d, const float* s) {
    float4 a = *(const float4*)s;
    float4 b = *(const float4*)(s + 4);
    bf16 t[8] = {(bf16)a.x, (bf16)a.y, (bf16)a.z, (bf16)a.w,
                 (bf16)b.x, (bf16)b.y, (bf16)b.z, (bf16)b.w};
    *(uint4*)d = *(const uint4*)t;
}

// ---------------- MFMA bf16 GEMM 64x64 tile, split-K, fp32 partials (emb, out_proj) ----
template <typename AT>
__global__ __launch_bounds__(256) void k_gemm_sk(const AT* __restrict__ A, int lda,
                                                 const float* __restrict__ W, int ldw,
                                                 const float* __restrict__ bias,
                                                 float* __restrict__ part,
                                                 int N, int Kh, int useBias)
{
    __shared__ __align__(16) short As[64][72];
    __shared__ __align__(16) short Ws[64][72];

    const int tid  = threadIdx.x;
    const int lane = tid & 63, wid = tid >> 6;
    const int wm = wid >> 1, wn = wid & 1;
    const int row0 = blockIdx.y * 64, col0 = blockIdx.x * 64;
    const int quad = lane >> 4, l16 = lane & 15;
    const int kbase = blockIdx.z * Kh;

    f32x4 acc[2][2] = {};
    for (int k0 = 0; k0 < Kh; k0 += 64) {
        #pragma unroll
        for (int i = 0; i < 2; i++) {
            int id = tid + i * 256;
            int r = id >> 3, g = id & 7;
            ld8(&As[r][g * 8], A + (size_t)(row0 + r) * lda + kbase + k0 + g * 8);
            ld8(&Ws[r][g * 8], W + (size_t)(col0 + r) * ldw + kbase + k0 + g * 8);
        }
        __syncthreads();
        #pragma unroll
        for (int ks = 0; ks < 64; ks += 32) {
            short8 af[2], bfr[2];
            #pragma unroll
            for (int i = 0; i < 2; i++) af[i] = *(const short8*)&As[wm * 32 + i * 16 + l16][ks + quad * 8];
            #pragma unroll
            for (int j = 0; j < 2; j++) bfr[j] = *(const short8*)&Ws[wn * 32 + j * 16 + l16][ks + quad * 8];
            #pragma unroll
            for (int i = 0; i < 2; i++)
                #pragma unroll
                for (int j = 0; j < 2; j++)
                    acc[i][j] = __builtin_amdgcn_mfma_f32_16x16x32_bf16(af[i], bfr[j], acc[i][j], 0, 0, 0);
        }
        __syncthreads();
    }
    float* pdst = part + (size_t)blockIdx.z * LSEQ * N;
    #pragma unroll
    for (int i = 0; i < 2; i++) {
        #pragma unroll
        for (int j = 0; j < 2; j++) {
            int gn = col0 + wn * 32 + j * 16 + l16;
            int gm0 = row0 + wm * 32 + i * 16 + quad * 4;
            #pragma unroll
            for (int r = 0; r < 4; r++) {
                float v = acc[i][j][r];
                if (useBias && blockIdx.z == 0) v += bias[gn];
                pdst[(size_t)(gm0 + r) * N + gn] = v;
            }
        }
    }
}

// ---------------- in_proj GEMM: no split-K, writes bf16 xz directly ----------------
__global__ __launch_bounds__(256) void k_gemm_skb(const bf16* __restrict__ A, int lda,
                                                  const float* __restrict__ W, int ldw,
                                                  bf16* __restrict__ outp,
                                                  int N, int Kh)
{
    __shared__ __align__(16) short As[64][72];
    __shared__ __align__(16) short Ws[64][72];

    const int tid  = threadIdx.x;
    const int lane = tid & 63, wid = tid >> 6;
    const int wm = wid >> 1, wn = wid & 1;
    const int row0 = blockIdx.y * 64, col0 = blockIdx.x * 64;
    const int quad = lane >> 4, l16 = lane & 15;

    f32x4 acc[2][2] = {};
    for (int k0 = 0; k0 < Kh; k0 += 64) {
        #pragma unroll
        for (int i = 0; i < 2; i++) {
            int id = tid + i * 256;
            int r = id >> 3, g = id & 7;
            ld8(&As[r][g * 8], A + (size_t)(row0 + r) * lda + k0 + g * 8);
            ld8(&Ws[r][g * 8], W + (size_t)(col0 + r) * ldw + k0 + g * 8);
        }
        __syncthreads();
        #pragma unroll
        for (int ks = 0; ks < 64; ks += 32) {
            short8 af[2], bfr[2];
            #pragma unroll
            for (int i = 0; i < 2; i++) af[i] = *(const short8*)&As[wm * 32 + i * 16 + l16][ks + quad * 8];
            #pragma unroll
            for (int j = 0; j < 2; j++) bfr[j] = *(const short8*)&Ws[wn * 32 + j * 16 + l16][ks + quad * 8];
            #pragma unroll
            for (int i = 0; i < 2; i++)
                #pragma unroll
                for (int j = 0; j < 2; j++)
                    acc[i][j] = __builtin_amdgcn_mfma_f32_16x16x32_bf16(af[i], bfr[j], acc[i][j], 0, 0, 0);
        }
        __syncthreads();
    }
    #pragma unroll
    for (int i = 0; i < 2; i++) {
        #pragma unroll
        for (int j = 0; j < 2; j++) {
            int gn = col0 + wn * 32 + j * 16 + l16;
            int gm0 = row0 + wm * 32 + i * 16 + quad * 4;
            #pragma unroll
            for (int r = 0; r < 4; r++)
                outp[(size_t)(gm0 + r) * N + gn] = (bf16)acc[i][j][r];
        }
    }
}

// ---------------- head GEMM: A = sum of two fp32 partials, W fp32 ----------------
__global__ __launch_bounds__(256) void k_gemm_h(const float* __restrict__ A0,
                                                const float* __restrict__ A1, int lda,
                                                const float* __restrict__ W, int ldw,
                                                const float* __restrict__ bias,
                                                float* __restrict__ out, int N, int Kd)
{
    __shared__ __align__(16) short As[64][72];
    __shared__ __align__(16) short Ws[64][72];

    const int tid  = threadIdx.x;
    const int lane = tid & 63, wid = tid >> 6;
    const int wm = wid >> 1, wn = wid & 1;
    const int row0 = blockIdx.y * 64, col0 = blockIdx.x * 64;
    const int quad = lane >> 4, l16 = lane & 15;

    f32x4 acc[2][2] = {};
    for (int k0 = 0; k0 < Kd; k0 += 64) {
        #pragma unroll
        for (int i = 0; i < 2; i++) {
            int id = tid + i * 256;
            int r = id >> 3, g = id & 7;
            size_t base = (size_t)(row0 + r) * lda + k0 + g * 8;
            float4 a0 = *(const float4*)(A0 + base);
            float4 a1 = *(const float4*)(A0 + base + 4);
            float4 b0 = *(const float4*)(A1 + base);
            float4 b1 = *(const float4*)(A1 + base + 4);
            bf16 tmp[8] = {(bf16)(a0.x + b0.x), (bf16)(a0.y + b0.y),
                           (bf16)(a0.z + b0.z), (bf16)(a0.w + b0.w),
                           (bf16)(a1.x + b1.x), (bf16)(a1.y + b1.y),
                           (bf16)(a1.z + b1.z), (bf16)(a1.w + b1.w)};
            *(uint4*)&As[r][g * 8] = *(const uint4*)tmp;
            ld8(&Ws[r][g * 8], W + (size_t)(col0 + r) * ldw + k0 + g * 8);
        }
        __syncthreads();
        #pragma unroll
        for (int ks = 0; ks < 64; ks += 32) {
            short8 af[2], bfr[2];
            #pragma unroll
            for (int i = 0; i < 2; i++) af[i] = *(const short8*)&As[wm * 32 + i * 16 + l16][ks + quad * 8];
            #pragma unroll
            for (int j = 0; j < 2; j++) bfr[j] = *(const short8*)&Ws[wn * 32 + j * 16 + l16][ks + quad * 8];
            #pragma unroll
            for (int i = 0; i < 2; i++)
                #pragma unroll
                for (int j = 0; j < 2; j++)
                    acc[i][j] = __builtin_amdgcn_mfma_f32_16x16x32_bf16(af[i], bfr[j], acc[i][j], 0, 0, 0);
        }
        __syncthreads();
    }
    #pragma unroll
    for (int i = 0; i < 2; i++) {
        #pragma unroll
        for (int j = 0; j < 2; j++) {
            int gn = col0 + wn * 32 + j * 16 + l16;
            int gm0 = row0 + wm * 32 + i * 16 + quad * 4;
            #pragma unroll
            for (int r = 0; r < 4; r++)
                out[(size_t)(gm0 + r) * N + gn] = acc[i][j][r] + bias[gn];
        }
    }
}

// ---------------- xproj GEMM with fused causal-conv+silu A-staging ----------------
__global__ __launch_bounds__(256) void k_xproj_conv(
    const bf16* __restrict__ xz,
    const float* __restrict__ W,     // x_proj fp32 [80][EDIM]
    const float* __restrict__ cw,    // [EDIM][4]
    const float* __restrict__ cb,    // [EDIM]
    float* __restrict__ part,
    bf16* __restrict__ ub)
{
    __shared__ __align__(16) short As[64][72];
    __shared__ __align__(16) short Ws[64][72];
    __shared__ __align__(16) bf16 Xr[67][64];

    const int tid  = threadIdx.x;
    const int lane = tid & 63, wid = tid >> 6;
    const int wm = wid >> 1, wn = wid & 1;
    const int row0 = blockIdx.y * 64, col0 = blockIdx.x * 64;
    const int quad = lane >> 4, l16 = lane & 15;
    const int kbase = blockIdx.z * XKCH;

    f32x4 acc[2][2] = {};
    for (int k0 = 0; k0 < XKCH; k0 += 64) {
        const int ecol = kbase + k0;
        for (int idx = tid; idx < 67 * 8; idx += 256) {
            int r = idx >> 3, g = idx & 7;
            int gr = row0 - 3 + r;
            uint4 v = {0, 0, 0, 0};
            if (gr >= 0) v = *(const uint4*)(xz + (size_t)gr * (2 * EDIM) + ecol + g * 8);
            *(uint4*)&Xr[r][g * 8] = v;
        }
        #pragma unroll
        for (int i = 0; i < 2; i++) {
            int id = tid + i * 256;
            int r = id >> 3, g = id & 7;
            if (col0 + r < 80) {
                ld8(&Ws[r][g * 8], W + (size_t)(col0 + r) * EDIM + ecol + g * 8);
            } else {
                uint4 z = {0, 0, 0, 0};
                *(uint4*)&Ws[r][g * 8] = z;
            }
        }
        __syncthreads();
        {
            const int e = tid & 63;
            const int rb = (tid >> 6) * 16;
            const float cw0 = cw[(ecol + e) * 4 + 0];
            const float cw1 = cw[(ecol + e) * 4 + 1];
            const float cw2 = cw[(ecol + e) * 4 + 2];
            const float cw3 = cw[(ecol + e) * 4 + 3];
            const float cbv = cb[ecol + e];
            #pragma unroll
            for (int j = 0; j < 16; j++) {
                int r = rb + j;
                float s = cbv
                        + cw0 * (float)Xr[r + 0][e]
                        + cw1 * (float)Xr[r + 1][e]
                        + cw2 * (float)Xr[r + 2][e]
                        + cw3 * (float)Xr[r + 3][e];
                bf16 h = (bf16)siluf(s);
                As[r][e] = *reinterpret_cast<short*>(&h);
            }
        }
        __syncthreads();
        if (blockIdx.x == 0) {
            for (int idx = tid; idx < 64 * 8; idx += 256) {
                int r = idx >> 3, g = idx & 7;
                *(uint4*)(ub + (size_t)(row0 + r) * EDIM + ecol + g * 8) = *(const uint4*)&As[r][g * 8];
            }
        }
        #pragma unroll
        for (int ks = 0; ks < 64; ks += 32) {
            short8 af[2], bfr[2];
            #pragma unroll
            for (int i = 0; i < 2; i++) af[i] = *(const short8*)&As[wm * 32 + i * 16 + l16][ks + quad * 8];
            #pragma unroll
            for (int j = 0; j < 2; j++) bfr[j] = *(const short8*)&Ws[wn * 32 + j * 16 + l16][ks + quad * 8];
            #pragma unroll
            for (int i = 0; i < 2; i++)
                #pragma unroll
                for (int j = 0; j < 2; j++)
                    acc[i][j] = __builtin_amdgcn_mfma_f32_16x16x32_bf16(af[i], bfr[j], acc[i][j], 0, 0, 0);
        }
        __syncthreads();
    }

    float* pdst = part + (size_t)blockIdx.z * (LSEQ * 80);
    #pragma unroll
    for (int i = 0; i < 2; i++) {
        #pragma unroll
        for (int j = 0; j < 2; j++) {
            int gn = col0 + wn * 32 + j * 16 + l16;
            int gm0 = row0 + wm * 32 + i * 16 + quad * 4;
            if (gn < 80) {
                #pragma unroll
                for (int r = 0; r < 4; r++)
                    pdst[(size_t)(gm0 + r) * 80 + gn] = acc[i][j][r];
            }
        }
    }
}

// ---------------- residual + rmsnorm ----------------
__global__ __launch_bounds__(256) void k_rms(const float* __restrict__ h0,
                                             const float* __restrict__ h1,
                                             float* __restrict__ res,
                                             bf16* __restrict__ hnb, const float* __restrict__ w,
                                             int first)
{
    __shared__ float red[4];
    __shared__ float tot;
    const int tid = threadIdx.x;
    const int t = blockIdx.x;
    float v[3]; float ss = 0.f;
    #pragma unroll
    for (int r = 0; r < 3; r++) {
        int j = tid + r * 256;
        float xv = h0[(size_t)t * HDIM + j] + h1[(size_t)t * HDIM + j];
        if (!first) xv += res[(size_t)t * HDIM + j];
        v[r] = xv;
        res[(size_t)t * HDIM + j] = xv;
        ss += xv * xv;
    }
    #pragma unroll
    for (int m = 32; m >= 1; m >>= 1) ss += __shfl_down(ss, m);
    int wid = tid >> 6;
    if ((tid & 63) == 0) red[wid] = ss;
    __syncthreads();
    if (tid == 0) tot = red[0] + red[1] + red[2] + red[3];
    __syncthreads();
    float scale = rsqrtf(tot / (float)HDIM + 1e-5f);
    #pragma unroll
    for (int r = 0; r < 3; r++) {
        int j = tid + r * 256;
        hnb[(size_t)t * HDIM + j] = (bf16)(v[r] * scale * w[j]);
    }
}

// ---------------- dt-GEMM from LDS slab (shared by scan1/scan3) ----------------
__device__ __forceinline__ void dt_gemm(
    const float* __restrict__ dtw, const float* __restrict__ dtbb,
    float (*A_red)[48], float (*dtL)[256], int e, int tid)
{
    const float* we = dtw + (size_t)e * RDIM;
    const float bb = dtbb[e];
    float acc[CHLEN] = {};
    #pragma unroll 3
    for (int k = 0; k < RDIM; k += 4) {
        float4 w4 = *(const float4*)(we + k);
        #pragma unroll
        for (int j = 0; j < CHLEN; j++) {
            float4 a4 = *(const float4*)&A_red[j][k];
            acc[j] += a4.x * w4.x + a4.y * w4.y + a4.z * w4.z + a4.w * w4.w;
        }
    }
    #pragma unroll
    for (int j = 0; j < CHLEN; j++)
        dtL[j][tid] = softplusf(acc[j] + bb);
}

// ---------------- scan1: 8-way part reduce + publish dbc + dt-GEMM + local scan ----
// Gather is done per-block (round-6 code); ex==0 blocks publish the reduced slab
// to dbc (round-7 code) so scan3 reads it with one coalesced load. This removes
// the separate k_red8 dispatch (round-10 measurement: ~8us gap per dispatch
// dominates; kernel-side giveback bounded <=4.6us by round-6/9 A/B).
__global__ __launch_bounds__(256) void k_scan1d(
    const float* __restrict__ part, const float* __restrict__ dtw,
    const float* __restrict__ dtbb,
    const bf16*  __restrict__ ub,
    const float* __restrict__ a_log,
    float* __restrict__ chunkS, float* __restrict__ sumdt,
    float* __restrict__ dbc)
{
    __shared__ __align__(16) float A_red[CHLEN][48];
    __shared__ __align__(16) float BC[CHLEN][32];
    __shared__ __align__(16) float dtL[CHLEN][256];
    const int tid = threadIdx.x;
    const int ex = blockIdx.x % 6, c = blockIdx.x / 6;
    const int e = ex * 256 + tid;
    const int t0 = c * CHLEN;

    for (int idx = tid; idx < CHLEN * 48; idx += 256) {
        int tt = idx / 48, k = idx - tt * 48;
        size_t o = (size_t)(t0 + tt) * 80 + k;
        float sv = 0.f;
        #pragma unroll
        for (int p = 0; p < XSPLIT; p++) sv += part[(size_t)p * (LSEQ * 80) + o];
        A_red[tt][k] = sv;
    }
    for (int idx = tid; idx < CHLEN * 32; idx += 256) {
        int tt = idx >> 5, k = idx & 31;
        size_t o = (size_t)(t0 + tt) * 80 + RDIM + k;
        float sv = 0.f;
        #pragma unroll
        for (int p = 0; p < XSPLIT; p++) sv += part[(size_t)p * (LSEQ * 80) + o];
        BC[tt][k] = sv;
    }
    __syncthreads();

    // publish reduced slab for scan3 (bitwise-identical values, LDS -> global copy)
    if (ex == 0) {
        for (int idx = tid; idx < CHLEN * 80; idx += 256) {
            int tt = idx / 80, k = idx - tt * 80;
            float v = (k < RDIM) ? A_red[tt][k] : BC[tt][k - RDIM];
            dbc[(size_t)(t0 + tt) * 80 + k] = v;
        }
    }

    dt_gemm(dtw, dtbb, A_red, dtL, e, tid);

    // prefetch u for the whole chunk (independent loads, batched issue)
    float u8[CHLEN];
    #pragma unroll
    for (int tt = 0; tt < CHLEN; tt++)
        u8[tt] = (float)ub[(size_t)(t0 + tt) * EDIM + e];

    float A[16];
    #pragma unroll
    for (int q = 0; q < 4; q++) {
        float4 a4 = *(const float4*)(a_log + (size_t)e * NDIM + q * 4);
        A[q*4+0] = -__expf(a4.x); A[q*4+1] = -__expf(a4.y);
        A[q*4+2] = -__expf(a4.z); A[q*4+3] = -__expf(a4.w);
    }
    float s[16] = {};
    float sd = 0.f;
    #pragma unroll
    for (int tt = 0; tt < CHLEN; tt++) {
        float dtv = dtL[tt][tid];
        float dtu = dtv * u8[tt];
        sd += dtv;
        #pragma unroll
        for (int n = 0; n < 16; n++) s[n] = s[n] * __expf(dtv * A[n]) + dtu * BC[tt][n];
    }
    float* cs = chunkS + ((size_t)c * EDIM + e) * NDIM;
    #pragma unroll
    for (int q = 0; q < 4; q++)
        *(float4*)(cs + q * 4) = make_float4(s[q*4+0], s[q*4+1], s[q*4+2], s[q*4+3]);
    sumdt[(size_t)c * EDIM + e] = sd;
}

// ---------------- scan2: two-level affine prefix over chunks -> sInit ----------------
__global__ __launch_bounds__(256) void k_scan2p(
    const float* __restrict__ chunkS, const float* __restrict__ sumdt,
    const float* __restrict__ a_log, float* __restrict__ sInit)
{
    __shared__ float sP[256];
    __shared__ float sX[256];
    const int tid = threadIdx.x;
    const int pl = tid & 63, q = tid >> 6;
    const int p = blockIdx.x * 64 + pl;   // pair index = e*16+n
    const int pe = p >> 4;
    const float Aen = -__expf(a_log[p]);
    float P[CPG], X[CPG];
    float Pc = 1.f, Xc = 0.f;
    #pragma unroll
    for (int j = 0; j < CPG; j++) {
        int cc = q * CPG + j;
        float Pj = __expf(Aen * sumdt[(size_t)cc * EDIM + pe]);
        float Xj = chunkS[(size_t)cc * (EDIM * NDIM) + p];
        P[j] = Pj; X[j] = Xj;
        Xc = Pj * Xc + Xj;
        Pc *= Pj;
    }
    sP[q * 64 + pl] = Pc;
    sX[q * 64 + pl] = Xc;
    __syncthreads();
    float s = 0.f;
    for (int g = 0; g < q; g++) s = sP[g * 64 + pl] * s + sX[g * 64 + pl];
    #pragma unroll
    for (int j = 0; j < CPG; j++) {
        int cc = q * CPG + j;
        sInit[(size_t)cc * (EDIM * NDIM) + p] = s;
        s = P[j] * s + X[j];
    }
}

// ---------------- scan3: dbc-sourced dt-GEMM + final scan with carry + y/z gating ----
__global__ __launch_bounds__(256) void k_scan3d(
    const float* __restrict__ dbc, const float* __restrict__ dtw,
    const float* __restrict__ dtbb,
    const bf16*  __restrict__ ub,
    const bf16*  __restrict__ xz,
    const float* __restrict__ a_log,
    const float* __restrict__ Dp,
    const float* __restrict__ sInit,
    bf16* __restrict__ yzb)
{
    __shared__ __align__(16) float A_red[CHLEN][48];
    __shared__ __align__(16) float BC[CHLEN][32];
    __shared__ __align__(16) float dtL[CHLEN][256];
    const int tid = threadIdx.x;
    const int ex = blockIdx.x % 6, c = blockIdx.x / 6;
    const int e = ex * 256 + tid;
    const int t0 = c * CHLEN;

    // single coalesced load of the pre-reduced slab
    for (int idx = tid; idx < CHLEN * 80; idx += 256) {
        int tt = idx / 80, k = idx - tt * 80;
        float v = dbc[(size_t)(t0 + tt) * 80 + k];
        if (k < RDIM) A_red[tt][k] = v; else BC[tt][k - RDIM] = v;
    }
    __syncthreads();

    dt_gemm(dtw, dtbb, A_red, dtL, e, tid);

    // prefetch u and z for the whole chunk (independent loads, batched issue)
    float u8[CHLEN], z8[CHLEN];
    #pragma unroll
    for (int tt = 0; tt < CHLEN; tt++) {
        u8[tt] = (float)ub[(size_t)(t0 + tt) * EDIM + e];
        z8[tt] = (float)xz[(size_t)(t0 + tt) * (2 * EDIM) + EDIM + e];
    }

    float A[16];
    #pragma unroll
    for (int q = 0; q < 4; q++) {
        float4 a4 = *(const float4*)(a_log + (size_t)e * NDIM + q * 4);
        A[q*4+0] = -__expf(a4.x); A[q*4+1] = -__expf(a4.y);
        A[q*4+2] = -__expf(a4.z); A[q*4+3] = -__expf(a4.w);
    }
    const float dv = Dp[e];
    float s[16];
    const float* si = sInit + ((size_t)c * EDIM + e) * NDIM;
    #pragma unroll
    for (int q = 0; q < 4; q++) {
        float4 s4 = *(const float4*)(si + q * 4);
        s[q*4+0] = s4.x; s[q*4+1] = s4.y; s[q*4+2] = s4.z; s[q*4+3] = s4.w;
    }
    #pragma unroll
    for (int tt = 0; tt < CHLEN; tt++) {
        float dtv = dtL[tt][tid];
        float uv  = u8[tt];
        float dtu = dtv * uv;
        float y = 0.f;
        #pragma unroll
        for (int n = 0; n < 16; n++) {
            s[n] = s[n] * __expf(dtv * A[n]) + dtu * BC[tt][n];
            y += s[n] * BC[tt][16 + n];
        }
        y += uv * dv;
        yzb[(size_t)(t0 + tt) * EDIM + e] = (bf16)(y * siluf(z8[tt]));
    }
}

extern "C" void kernel_launch(void* const* d_in, const int* in_sizes, int n_in,
                              void* d_out, int out_size, void* d_ws, size_t ws_size,
                              hipStream_t stream)
{
    const float* x        = (const float*)d_in[0];
    const float* emb_w    = (const float*)d_in[1];
    const float* emb_b    = (const float*)d_in[2];
    const float* norm_w   = (const float*)d_in[3];
    const float* in_proj  = (const float*)d_in[4];
    const float* conv_w   = (const float*)d_in[5];
    const float* conv_b   = (const float*)d_in[6];
    const float* x_proj   = (const float*)d_in[7];
    const float* dt_w     = (const float*)d_in[8];
    const float* dt_b     = (const float*)d_in[9];
    const float* A_log    = (const float*)d_in[10];
    const float* Dp       = (const float*)d_in[11];
    const float* out_proj = (const float*)d_in[12];
    const float* head_w   = (const float*)d_in[13];
    const float* head_b   = (const float*)d_in[14];
    float* out = (float*)d_out;

    float* ws = (float*)d_ws;
    size_t off = 0;
    float* hpart  = ws + off; off += (size_t)2 * LSEQ * HDIM;
    float* res    = ws + off; off += (size_t)LSEQ * HDIM;
    float* part   = ws + off; off += (size_t)XSPLIT * LSEQ * 80;
    float* dbc    = ws + off; off += (size_t)LSEQ * 80;
    float* chunkS = ws + off; off += (size_t)NCHUNK * EDIM * NDIM;
    float* sumdt  = ws + off; off += (size_t)NCHUNK * EDIM;
    float* sInit  = ws + off; off += (size_t)NCHUNK * EDIM * NDIM;
    bf16* xz      = (bf16*)(ws + off); off += (size_t)LSEQ * 2 * EDIM / 2;
    bf16* hnb     = (bf16*)(ws + off); off += (size_t)LSEQ * HDIM / 2;
    bf16* yzb     = (bf16*)(ws + off); off += (size_t)LSEQ * EDIM / 2;
    bf16* ub      = (bf16*)(ws + off); off += (size_t)LSEQ * EDIM / 2;

    // embed: split-K=2 (Kh=128) -> hpart[2]
    k_gemm_sk<float><<<dim3(12, 16, 2), 256, 0, stream>>>(x, SDIM, emb_w, SDIM, emb_b,
                                                          hpart, HDIM, SDIM / 2, 1);

    for (int l = 0; l < NLAYER; l++) {
        const float* inw  = in_proj  + (size_t)l * 2 * EDIM * HDIM;
        const float* outw = out_proj + (size_t)l * HDIM * EDIM;
        const float* xwl  = x_proj   + (size_t)l * 80 * EDIM;
        const float* cw   = conv_w   + (size_t)l * EDIM * KCONV;
        const float* cb   = conv_b   + (size_t)l * EDIM;
        const float* dtw  = dt_w     + (size_t)l * EDIM * RDIM;
        const float* dtbb = dt_b     + (size_t)l * EDIM;
        const float* al   = A_log    + (size_t)l * EDIM * NDIM;
        const float* Dpl  = Dp       + (size_t)l * EDIM;

        k_rms<<<LSEQ, 256, 0, stream>>>(hpart, hpart + (size_t)LSEQ * HDIM, res,
                                        hnb, norm_w + (size_t)l * HDIM, l == 0);
        // in_proj: full-K (768), 64x64 tile, single bf16 xz output; 768 blocks
        k_gemm_skb<<<dim3(48, 16, 1), 256, 0, stream>>>(hnb, HDIM, inw, HDIM,
                                                        xz, 2 * EDIM, HDIM);
        // xproj with fused conv+silu; writes split-K partials + ub
        k_xproj_conv<<<dim3(2, 16, XSPLIT), 256, 0, stream>>>(xz, xwl, cw, cb, part, ub);
        // scan: 3 kernels; scan1 gathers part + publishes dbc (no k_red8 dispatch)
        k_scan1d<<<6 * NCHUNK, 256, 0, stream>>>(part, dtw, dtbb, ub, al,
                                                 chunkS, sumdt, dbc);
        k_scan2p<<<EDIM * NDIM / 64, 256, 0, stream>>>(chunkS, sumdt, al, sInit);
        k_scan3d<<<6 * NCHUNK, 256, 0, stream>>>(dbc, dtw, dtbb, ub, xz, al, Dpl,
                                                 sInit, yzb);
        // out_proj: split-K=2 (Kh=768) -> hpart[2]
        k_gemm_sk<bf16><<<dim3(12, 16, 2), 256, 0, stream>>>(yzb, EDIM, outw, EDIM, nullptr,
                                                             hpart, HDIM, EDIM / 2, 0);
    }

    // head: A = hpart0 + hpart1 (fp32), W fp32 converted in staging
    k_gemm_h<<<dim3(4, 16), 256, 0, stream>>>(hpart, hpart + (size_t)LSEQ * HDIM, HDIM,
                                              head_w, HDIM, head_b, out, SDIM, HDIM);
}

// Round 13
// 324.332 us; speedup vs baseline: 2.6048x; 1.0559x over previous
//
#include <hip/hip_runtime.h>
#include <hip/hip_bf16.h>
#include <math.h>

// Problem dims
#define SDIM 256
#define HDIM 768
#define EDIM 1536
#define NDIM 16
#define KCONV 4
#define RDIM 48
#define NLAYER 2
#define LSEQ 1024

#define NCHUNK 128
#define CHLEN (LSEQ / NCHUNK)   // 8
#define CPG (NCHUNK / 4)        // 32 chunks per prefix group
#define XSPLIT 8
#define XKCH (EDIM / XSPLIT)    // 192
#define HSPLIT 4                // split-K for emb/out_proj (r10: 1.5 blk/CU was the limiter)

typedef __hip_bfloat16 bf16;
typedef __attribute__((ext_vector_type(8))) short short8;
typedef __attribute__((ext_vector_type(4))) float f32x4;

__device__ __forceinline__ float softplusf(float x) {
    return (x > 20.f) ? x : log1pf(expf(x));
}
__device__ __forceinline__ float siluf(float x) {
    return x / (1.f + expf(-x));
}

// stage 8 elements into LDS as bf16 (bf16 source: raw copy; fp32 source: convert)
__device__ __forceinline__ void ld8(short* d, const bf16* s) {
    *(uint4*)d = *(const uint4*)s;
}
__device__ __forceinline__ void ld8(short* d, const float* s) {
    float4 a = *(const float4*)s;
    float4 b = *(const float4*)(s + 4);
    bf16 t[8] = {(bf16)a.x, (bf16)a.y, (bf16)a.z, (bf16)a.w,
                 (bf16)b.x, (bf16)b.y, (bf16)b.z, (bf16)b.w};
    *(uint4*)d = *(const uint4*)t;
}

// ---------------- MFMA bf16 GEMM 64x64 tile, split-K, fp32 partials (emb, out_proj) ----
template <typename AT>
__global__ __launch_bounds__(256) void k_gemm_sk(const AT* __restrict__ A, int lda,
                                                 const float* __restrict__ W, int ldw,
                                                 const float* __restrict__ bias,
                                                 float* __restrict__ part,
                                                 int N, int Kh, int useBias)
{
    __shared__ __align__(16) short As[64][72];
    __shared__ __align__(16) short Ws[64][72];

    const int tid  = threadIdx.x;
    const int lane = tid & 63, wid = tid >> 6;
    const int wm = wid >> 1, wn = wid & 1;
    const int row0 = blockIdx.y * 64, col0 = blockIdx.x * 64;
    const int quad = lane >> 4, l16 = lane & 15;
    const int kbase = blockIdx.z * Kh;

    f32x4 acc[2][2] = {};
    for (int k0 = 0; k0 < Kh; k0 += 64) {
        #pragma unroll
        for (int i = 0; i < 2; i++) {
            int id = tid + i * 256;
            int r = id >> 3, g = id & 7;
            ld8(&As[r][g * 8], A + (size_t)(row0 + r) * lda + kbase + k0 + g * 8);
            ld8(&Ws[r][g * 8], W + (size_t)(col0 + r) * ldw + kbase + k0 + g * 8);
        }
        __syncthreads();
        #pragma unroll
        for (int ks = 0; ks < 64; ks += 32) {
            short8 af[2], bfr[2];
            #pragma unroll
            for (int i = 0; i < 2; i++) af[i] = *(const short8*)&As[wm * 32 + i * 16 + l16][ks + quad * 8];
            #pragma unroll
            for (int j = 0; j < 2; j++) bfr[j] = *(const short8*)&Ws[wn * 32 + j * 16 + l16][ks + quad * 8];
            #pragma unroll
            for (int i = 0; i < 2; i++)
                #pragma unroll
                for (int j = 0; j < 2; j++)
                    acc[i][j] = __builtin_amdgcn_mfma_f32_16x16x32_bf16(af[i], bfr[j], acc[i][j], 0, 0, 0);
        }
        __syncthreads();
    }
    float* pdst = part + (size_t)blockIdx.z * LSEQ * N;
    #pragma unroll
    for (int i = 0; i < 2; i++) {
        #pragma unroll
        for (int j = 0; j < 2; j++) {
            int gn = col0 + wn * 32 + j * 16 + l16;
            int gm0 = row0 + wm * 32 + i * 16 + quad * 4;
            #pragma unroll
            for (int r = 0; r < 4; r++) {
                float v = acc[i][j][r];
                if (useBias && blockIdx.z == 0) v += bias[gn];
                pdst[(size_t)(gm0 + r) * N + gn] = v;
            }
        }
    }
}

// ---------------- in_proj GEMM: no split-K, writes bf16 xz directly ----------------
__global__ __launch_bounds__(256) void k_gemm_skb(const bf16* __restrict__ A, int lda,
                                                  const float* __restrict__ W, int ldw,
                                                  bf16* __restrict__ outp,
                                                  int N, int Kh)
{
    __shared__ __align__(16) short As[64][72];
    __shared__ __align__(16) short Ws[64][72];

    const int tid  = threadIdx.x;
    const int lane = tid & 63, wid = tid >> 6;
    const int wm = wid >> 1, wn = wid & 1;
    const int row0 = blockIdx.y * 64, col0 = blockIdx.x * 64;
    const int quad = lane >> 4, l16 = lane & 15;

    f32x4 acc[2][2] = {};
    for (int k0 = 0; k0 < Kh; k0 += 64) {
        #pragma unroll
        for (int i = 0; i < 2; i++) {
            int id = tid + i * 256;
            int r = id >> 3, g = id & 7;
            ld8(&As[r][g * 8], A + (size_t)(row0 + r) * lda + k0 + g * 8);
            ld8(&Ws[r][g * 8], W + (size_t)(col0 + r) * ldw + k0 + g * 8);
        }
        __syncthreads();
        #pragma unroll
        for (int ks = 0; ks < 64; ks += 32) {
            short8 af[2], bfr[2];
            #pragma unroll
            for (int i = 0; i < 2; i++) af[i] = *(const short8*)&As[wm * 32 + i * 16 + l16][ks + quad * 8];
            #pragma unroll
            for (int j = 0; j < 2; j++) bfr[j] = *(const short8*)&Ws[wn * 32 + j * 16 + l16][ks + quad * 8];
            #pragma unroll
            for (int i = 0; i < 2; i++)
                #pragma unroll
                for (int j = 0; j < 2; j++)
                    acc[i][j] = __builtin_amdgcn_mfma_f32_16x16x32_bf16(af[i], bfr[j], acc[i][j], 0, 0, 0);
        }
        __syncthreads();
    }
    #pragma unroll
    for (int i = 0; i < 2; i++) {
        #pragma unroll
        for (int j = 0; j < 2; j++) {
            int gn = col0 + wn * 32 + j * 16 + l16;
            int gm0 = row0 + wm * 32 + i * 16 + quad * 4;
            #pragma unroll
            for (int r = 0; r < 4; r++)
                outp[(size_t)(gm0 + r) * N + gn] = (bf16)acc[i][j][r];
        }
    }
}

// ---------------- head GEMM: A = sum of 4 fp32 partials, W fp32 ----------------
__global__ __launch_bounds__(256) void k_gemm_h(const float* __restrict__ hp, int lda,
                                                const float* __restrict__ W, int ldw,
                                                const float* __restrict__ bias,
                                                float* __restrict__ out, int N, int Kd)
{
    __shared__ __align__(16) short As[64][72];
    __shared__ __align__(16) short Ws[64][72];

    const int tid  = threadIdx.x;
    const int lane = tid & 63, wid = tid >> 6;
    const int wm = wid >> 1, wn = wid & 1;
    const int row0 = blockIdx.y * 64, col0 = blockIdx.x * 64;
    const int quad = lane >> 4, l16 = lane & 15;
    const size_t LH = (size_t)LSEQ * HDIM;

    f32x4 acc[2][2] = {};
    for (int k0 = 0; k0 < Kd; k0 += 64) {
        #pragma unroll
        for (int i = 0; i < 2; i++) {
            int id = tid + i * 256;
            int r = id >> 3, g = id & 7;
            size_t base = (size_t)(row0 + r) * lda + k0 + g * 8;
            float4 a0 = *(const float4*)(hp + base);
            float4 a1 = *(const float4*)(hp + LH + base);
            float4 a2 = *(const float4*)(hp + 2 * LH + base);
            float4 a3 = *(const float4*)(hp + 3 * LH + base);
            float4 b0 = *(const float4*)(hp + base + 4);
            float4 b1 = *(const float4*)(hp + LH + base + 4);
            float4 b2 = *(const float4*)(hp + 2 * LH + base + 4);
            float4 b3 = *(const float4*)(hp + 3 * LH + base + 4);
            bf16 tmp[8] = {(bf16)(a0.x + a1.x + a2.x + a3.x), (bf16)(a0.y + a1.y + a2.y + a3.y),
                           (bf16)(a0.z + a1.z + a2.z + a3.z), (bf16)(a0.w + a1.w + a2.w + a3.w),
                           (bf16)(b0.x + b1.x + b2.x + b3.x), (bf16)(b0.y + b1.y + b2.y + b3.y),
                           (bf16)(b0.z + b1.z + b2.z + b3.z), (bf16)(b0.w + b1.w + b2.w + b3.w)};
            *(uint4*)&As[r][g * 8] = *(const uint4*)tmp;
            ld8(&Ws[r][g * 8], W + (size_t)(col0 + r) * ldw + k0 + g * 8);
        }
        __syncthreads();
        #pragma unroll
        for (int ks = 0; ks < 64; ks += 32) {
            short8 af[2], bfr[2];
            #pragma unroll
            for (int i = 0; i < 2; i++) af[i] = *(const short8*)&As[wm * 32 + i * 16 + l16][ks + quad * 8];
            #pragma unroll
            for (int j = 0; j < 2; j++) bfr[j] = *(const short8*)&Ws[wn * 32 + j * 16 + l16][ks + quad * 8];
            #pragma unroll
            for (int i = 0; i < 2; i++)
                #pragma unroll
                for (int j = 0; j < 2; j++)
                    acc[i][j] = __builtin_amdgcn_mfma_f32_16x16x32_bf16(af[i], bfr[j], acc[i][j], 0, 0, 0);
        }
        __syncthreads();
    }
    #pragma unroll
    for (int i = 0; i < 2; i++) {
        #pragma unroll
        for (int j = 0; j < 2; j++) {
            int gn = col0 + wn * 32 + j * 16 + l16;
            int gm0 = row0 + wm * 32 + i * 16 + quad * 4;
            #pragma unroll
            for (int r = 0; r < 4; r++)
                out[(size_t)(gm0 + r) * N + gn] = acc[i][j][r] + bias[gn];
        }
    }
}

// ---------------- xproj GEMM with fused causal-conv+silu A-staging ----------------
__global__ __launch_bounds__(256) void k_xproj_conv(
    const bf16* __restrict__ xz,
    const float* __restrict__ W,     // x_proj fp32 [80][EDIM]
    const float* __restrict__ cw,    // [EDIM][4]
    const float* __restrict__ cb,    // [EDIM]
    float* __restrict__ part,
    bf16* __restrict__ ub)
{
    __shared__ __align__(16) short As[64][72];
    __shared__ __align__(16) short Ws[64][72];
    __shared__ __align__(16) bf16 Xr[67][64];

    const int tid  = threadIdx.x;
    const int lane = tid & 63, wid = tid >> 6;
    const int wm = wid >> 1, wn = wid & 1;
    const int row0 = blockIdx.y * 64, col0 = blockIdx.x * 64;
    const int quad = lane >> 4, l16 = lane & 15;
    const int kbase = blockIdx.z * XKCH;

    f32x4 acc[2][2] = {};
    for (int k0 = 0; k0 < XKCH; k0 += 64) {
        const int ecol = kbase + k0;
        for (int idx = tid; idx < 67 * 8; idx += 256) {
            int r = idx >> 3, g = idx & 7;
            int gr = row0 - 3 + r;
            uint4 v = {0, 0, 0, 0};
            if (gr >= 0) v = *(const uint4*)(xz + (size_t)gr * (2 * EDIM) + ecol + g * 8);
            *(uint4*)&Xr[r][g * 8] = v;
        }
        #pragma unroll
        for (int i = 0; i < 2; i++) {
            int id = tid + i * 256;
            int r = id >> 3, g = id & 7;
            if (col0 + r < 80) {
                ld8(&Ws[r][g * 8], W + (size_t)(col0 + r) * EDIM + ecol + g * 8);
            } else {
                uint4 z = {0, 0, 0, 0};
                *(uint4*)&Ws[r][g * 8] = z;
            }
        }
        __syncthreads();
        {
            const int e = tid & 63;
            const int rb = (tid >> 6) * 16;
            const float cw0 = cw[(ecol + e) * 4 + 0];
            const float cw1 = cw[(ecol + e) * 4 + 1];
            const float cw2 = cw[(ecol + e) * 4 + 2];
            const float cw3 = cw[(ecol + e) * 4 + 3];
            const float cbv = cb[ecol + e];
            #pragma unroll
            for (int j = 0; j < 16; j++) {
                int r = rb + j;
                float s = cbv
                        + cw0 * (float)Xr[r + 0][e]
                        + cw1 * (float)Xr[r + 1][e]
                        + cw2 * (float)Xr[r + 2][e]
                        + cw3 * (float)Xr[r + 3][e];
                bf16 h = (bf16)siluf(s);
                As[r][e] = *reinterpret_cast<short*>(&h);
            }
        }
        __syncthreads();
        if (blockIdx.x == 0) {
            for (int idx = tid; idx < 64 * 8; idx += 256) {
                int r = idx >> 3, g = idx & 7;
                *(uint4*)(ub + (size_t)(row0 + r) * EDIM + ecol + g * 8) = *(const uint4*)&As[r][g * 8];
            }
        }
        #pragma unroll
        for (int ks = 0; ks < 64; ks += 32) {
            short8 af[2], bfr[2];
            #pragma unroll
            for (int i = 0; i < 2; i++) af[i] = *(const short8*)&As[wm * 32 + i * 16 + l16][ks + quad * 8];
            #pragma unroll
            for (int j = 0; j < 2; j++) bfr[j] = *(const short8*)&Ws[wn * 32 + j * 16 + l16][ks + quad * 8];
            #pragma unroll
            for (int i = 0; i < 2; i++)
                #pragma unroll
                for (int j = 0; j < 2; j++)
                    acc[i][j] = __builtin_amdgcn_mfma_f32_16x16x32_bf16(af[i], bfr[j], acc[i][j], 0, 0, 0);
        }
        __syncthreads();
    }

    float* pdst = part + (size_t)blockIdx.z * (LSEQ * 80);
    #pragma unroll
    for (int i = 0; i < 2; i++) {
        #pragma unroll
        for (int j = 0; j < 2; j++) {
            int gn = col0 + wn * 32 + j * 16 + l16;
            int gm0 = row0 + wm * 32 + i * 16 + quad * 4;
            if (gn < 80) {
                #pragma unroll
                for (int r = 0; r < 4; r++)
                    pdst[(size_t)(gm0 + r) * 80 + gn] = acc[i][j][r];
            }
        }
    }
}

// ---------------- split-K reduce: part[8][LSEQ][80] -> dbc[LSEQ][80] ----------------
__global__ __launch_bounds__(256) void k_red8(const float* __restrict__ part,
                                              float* __restrict__ dbc)
{
    const int i = (blockIdx.x * 256 + threadIdx.x) * 4;
    float4 s = *(const float4*)(part + i);
    #pragma unroll
    for (int p = 1; p < XSPLIT; p++) {
        float4 v = *(const float4*)(part + (size_t)p * (LSEQ * 80) + i);
        s.x += v.x; s.y += v.y; s.z += v.z; s.w += v.w;
    }
    *(float4*)(dbc + i) = s;
}

// ---------------- residual + rmsnorm (sums HSPLIT=4 partials) ----------------
__global__ __launch_bounds__(256) void k_rms(const float* __restrict__ hp,
                                             float* __restrict__ res,
                                             bf16* __restrict__ hnb, const float* __restrict__ w,
                                             int first)
{
    __shared__ float red[4];
    __shared__ float tot;
    const int tid = threadIdx.x;
    const int t = blockIdx.x;
    const size_t LH = (size_t)LSEQ * HDIM;
    float v[3]; float ss = 0.f;
    #pragma unroll
    for (int r = 0; r < 3; r++) {
        int j = tid + r * 256;
        size_t o = (size_t)t * HDIM + j;
        float xv = hp[o] + hp[LH + o] + hp[2 * LH + o] + hp[3 * LH + o];
        if (!first) xv += res[o];
        v[r] = xv;
        res[o] = xv;
        ss += xv * xv;
    }
    #pragma unroll
    for (int m = 32; m >= 1; m >>= 1) ss += __shfl_down(ss, m);
    int wid = tid >> 6;
    if ((tid & 63) == 0) red[wid] = ss;
    __syncthreads();
    if (tid == 0) tot = red[0] + red[1] + red[2] + red[3];
    __syncthreads();
    float scale = rsqrtf(tot / (float)HDIM + 1e-5f);
    #pragma unroll
    for (int r = 0; r < 3; r++) {
        int j = tid + r * 256;
        hnb[(size_t)t * HDIM + j] = (bf16)(v[r] * scale * w[j]);
    }
}

// ---------------- shared helper: per-block dt/B/C tile from reduced dbc ----------
__device__ __forceinline__ void dt_tile(
    const float* __restrict__ dbc, const float* __restrict__ dtw,
    const float* __restrict__ dtbb,
    float (*A_red)[48], float (*BC)[32], float (*dtL)[256],
    int t0, int e, int tid)
{
    for (int idx = tid; idx < CHLEN * 80; idx += 256) {
        int tt = idx / 80, k = idx - tt * 80;
        float v = dbc[(size_t)(t0 + tt) * 80 + k];
        if (k < RDIM) A_red[tt][k] = v; else BC[tt][k - RDIM] = v;
    }
    __syncthreads();
    const float* we = dtw + (size_t)e * RDIM;
    const float bb = dtbb[e];
    float acc[CHLEN] = {};
    #pragma unroll 3
    for (int k = 0; k < RDIM; k += 4) {
        float4 w4 = *(const float4*)(we + k);
        #pragma unroll
        for (int j = 0; j < CHLEN; j++) {
            float4 a4 = *(const float4*)&A_red[j][k];
            acc[j] += a4.x * w4.x + a4.y * w4.y + a4.z * w4.z + a4.w * w4.w;
        }
    }
    #pragma unroll
    for (int j = 0; j < CHLEN; j++)
        dtL[j][tid] = softplusf(acc[j] + bb);
}

// ---------------- scan1: dt-GEMM + per-chunk local scan ----------------
__global__ __launch_bounds__(256) void k_scan1d(
    const float* __restrict__ dbc, const float* __restrict__ dtw,
    const float* __restrict__ dtbb,
    const bf16*  __restrict__ ub,
    const float* __restrict__ a_log,
    float* __restrict__ chunkS, float* __restrict__ sumdt)
{
    __shared__ __align__(16) float A_red[CHLEN][48];
    __shared__ __align__(16) float BC[CHLEN][32];
    __shared__ __align__(16) float dtL[CHLEN][256];
    const int tid = threadIdx.x;
    const int ex = blockIdx.x % 6, c = blockIdx.x / 6;
    const int e = ex * 256 + tid;
    const int t0 = c * CHLEN;

    dt_tile(dbc, dtw, dtbb, A_red, BC, dtL, t0, e, tid);

    // prefetch u for the whole chunk (independent loads, batched issue)
    float u8[CHLEN];
    #pragma unroll
    for (int tt = 0; tt < CHLEN; tt++)
        u8[tt] = (float)ub[(size_t)(t0 + tt) * EDIM + e];

    float A[16];
    #pragma unroll
    for (int q = 0; q < 4; q++) {
        float4 a4 = *(const float4*)(a_log + (size_t)e * NDIM + q * 4);
        A[q*4+0] = -__expf(a4.x); A[q*4+1] = -__expf(a4.y);
        A[q*4+2] = -__expf(a4.z); A[q*4+3] = -__expf(a4.w);
    }
    float s[16] = {};
    float sd = 0.f;
    #pragma unroll
    for (int tt = 0; tt < CHLEN; tt++) {
        float dtv = dtL[tt][tid];
        float dtu = dtv * u8[tt];
        sd += dtv;
        #pragma unroll
        for (int n = 0; n < 16; n++) s[n] = s[n] * __expf(dtv * A[n]) + dtu * BC[tt][n];
    }
    float* cs = chunkS + ((size_t)c * EDIM + e) * NDIM;
    #pragma unroll
    for (int q = 0; q < 4; q++)
        *(float4*)(cs + q * 4) = make_float4(s[q*4+0], s[q*4+1], s[q*4+2], s[q*4+3]);
    sumdt[(size_t)c * EDIM + e] = sd;
}

// ---------------- scan2: two-level affine prefix over chunks -> sInit ----------------
__global__ __launch_bounds__(256) void k_scan2p(
    const float* __restrict__ chunkS, const float* __restrict__ sumdt,
    const float* __restrict__ a_log, float* __restrict__ sInit)
{
    __shared__ float sP[256];
    __shared__ float sX[256];
    const int tid = threadIdx.x;
    const int pl = tid & 63, q = tid >> 6;
    const int p = blockIdx.x * 64 + pl;   // pair index = e*16+n
    const int pe = p >> 4;
    const float Aen = -__expf(a_log[p]);
    float P[CPG], X[CPG];
    float Pc = 1.f, Xc = 0.f;
    #pragma unroll
    for (int j = 0; j < CPG; j++) {
        int cc = q * CPG + j;
        float Pj = __expf(Aen * sumdt[(size_t)cc * EDIM + pe]);
        float Xj = chunkS[(size_t)cc * (EDIM * NDIM) + p];
        P[j] = Pj; X[j] = Xj;
        Xc = Pj * Xc + Xj;
        Pc *= Pj;
    }
    sP[q * 64 + pl] = Pc;
    sX[q * 64 + pl] = Xc;
    __syncthreads();
    float s = 0.f;
    for (int g = 0; g < q; g++) s = sP[g * 64 + pl] * s + sX[g * 64 + pl];
    #pragma unroll
    for (int j = 0; j < CPG; j++) {
        int cc = q * CPG + j;
        sInit[(size_t)cc * (EDIM * NDIM) + p] = s;
        s = P[j] * s + X[j];
    }
}

// ---------------- scan3: dt-GEMM + final scan with carry + y/z gating ----------
__global__ __launch_bounds__(256) void k_scan3d(
    const float* __restrict__ dbc, const float* __restrict__ dtw,
    const float* __restrict__ dtbb,
    const bf16*  __restrict__ ub,
    const bf16*  __restrict__ xz,
    const float* __restrict__ a_log,
    const float* __restrict__ Dp,
    const float* __restrict__ sInit,
    bf16* __restrict__ yzb)
{
    __shared__ __align__(16) float A_red[CHLEN][48];
    __shared__ __align__(16) float BC[CHLEN][32];
    __shared__ __align__(16) float dtL[CHLEN][256];
    const int tid = threadIdx.x;
    const int ex = blockIdx.x % 6, c = blockIdx.x / 6;
    const int e = ex * 256 + tid;
    const int t0 = c * CHLEN;

    dt_tile(dbc, dtw, dtbb, A_red, BC, dtL, t0, e, tid);

    // prefetch u and z for the whole chunk (independent loads, batched issue)
    float u8[CHLEN], z8[CHLEN];
    #pragma unroll
    for (int tt = 0; tt < CHLEN; tt++) {
        u8[tt] = (float)ub[(size_t)(t0 + tt) * EDIM + e];
        z8[tt] = (float)xz[(size_t)(t0 + tt) * (2 * EDIM) + EDIM + e];
    }

    float A[16];
    #pragma unroll
    for (int q = 0; q < 4; q++) {
        float4 a4 = *(const float4*)(a_log + (size_t)e * NDIM + q * 4);
        A[q*4+0] = -__expf(a4.x); A[q*4+1] = -__expf(a4.y);
        A[q*4+2] = -__expf(a4.z); A[q*4+3] = -__expf(a4.w);
    }
    const float dv = Dp[e];
    float s[16];
    const float* si = sInit + ((size_t)c * EDIM + e) * NDIM;
    #pragma unroll
    for (int q = 0; q < 4; q++) {
        float4 s4 = *(const float4*)(si + q * 4);
        s[q*4+0] = s4.x; s[q*4+1] = s4.y; s[q*4+2] = s4.z; s[q*4+3] = s4.w;
    }
    #pragma unroll
    for (int tt = 0; tt < CHLEN; tt++) {
        float dtv = dtL[tt][tid];
        float uv  = u8[tt];
        float dtu = dtv * uv;
        float y = 0.f;
        #pragma unroll
        for (int n = 0; n < 16; n++) {
            s[n] = s[n] * __expf(dtv * A[n]) + dtu * BC[tt][n];
            y += s[n] * BC[tt][16 + n];
        }
        y += uv * dv;
        yzb[(size_t)(t0 + tt) * EDIM + e] = (bf16)(y * siluf(z8[tt]));
    }
}

extern "C" void kernel_launch(void* const* d_in, const int* in_sizes, int n_in,
                              void* d_out, int out_size, void* d_ws, size_t ws_size,
                              hipStream_t stream)
{
    const float* x        = (const float*)d_in[0];
    const float* emb_w    = (const float*)d_in[1];
    const float* emb_b    = (const float*)d_in[2];
    const float* norm_w   = (const float*)d_in[3];
    const float* in_proj  = (const float*)d_in[4];
    const float* conv_w   = (const float*)d_in[5];
    const float* conv_b   = (const float*)d_in[6];
    const float* x_proj   = (const float*)d_in[7];
    const float* dt_w     = (const float*)d_in[8];
    const float* dt_b     = (const float*)d_in[9];
    const float* A_log    = (const float*)d_in[10];
    const float* Dp       = (const float*)d_in[11];
    const float* out_proj = (const float*)d_in[12];
    const float* head_w   = (const float*)d_in[13];
    const float* head_b   = (const float*)d_in[14];
    float* out = (float*)d_out;

    float* ws = (float*)d_ws;
    size_t off = 0;
    float* hpart  = ws + off; off += (size_t)HSPLIT * LSEQ * HDIM;
    float* res    = ws + off; off += (size_t)LSEQ * HDIM;
    float* part   = ws + off; off += (size_t)XSPLIT * LSEQ * 80;
    float* dbc    = ws + off; off += (size_t)LSEQ * 80;
    float* chunkS = ws + off; off += (size_t)NCHUNK * EDIM * NDIM;
    float* sumdt  = ws + off; off += (size_t)NCHUNK * EDIM;
    float* sInit  = ws + off; off += (size_t)NCHUNK * EDIM * NDIM;
    bf16* xz      = (bf16*)(ws + off); off += (size_t)LSEQ * 2 * EDIM / 2;
    bf16* hnb     = (bf16*)(ws + off); off += (size_t)LSEQ * HDIM / 2;
    bf16* yzb     = (bf16*)(ws + off); off += (size_t)LSEQ * EDIM / 2;
    bf16* ub      = (bf16*)(ws + off); off += (size_t)LSEQ * EDIM / 2;

    // embed: split-K=4 (Kh=64) -> hpart[4]; 768 blocks (3/CU)
    k_gemm_sk<float><<<dim3(12, 16, HSPLIT), 256, 0, stream>>>(x, SDIM, emb_w, SDIM, emb_b,
                                                               hpart, HDIM, SDIM / HSPLIT, 1);

    for (int l = 0; l < NLAYER; l++) {
        const float* inw  = in_proj  + (size_t)l * 2 * EDIM * HDIM;
        const float* outw = out_proj + (size_t)l * HDIM * EDIM;
        const float* xwl  = x_proj   + (size_t)l * 80 * EDIM;
        const float* cw   = conv_w   + (size_t)l * EDIM * KCONV;
        const float* cb   = conv_b   + (size_t)l * EDIM;
        const float* dtw  = dt_w     + (size_t)l * EDIM * RDIM;
        const float* dtbb = dt_b     + (size_t)l * EDIM;
        const float* al   = A_log    + (size_t)l * EDIM * NDIM;
        const float* Dpl  = Dp       + (size_t)l * EDIM;

        k_rms<<<LSEQ, 256, 0, stream>>>(hpart, res, hnb, norm_w + (size_t)l * HDIM, l == 0);
        // in_proj: full-K (768), 64x64 tile, single bf16 xz output; 768 blocks
        k_gemm_skb<<<dim3(48, 16, 1), 256, 0, stream>>>(hnb, HDIM, inw, HDIM,
                                                        xz, 2 * EDIM, HDIM);
        // xproj with fused conv+silu; writes split-K partials + ub
        k_xproj_conv<<<dim3(2, 16, XSPLIT), 256, 0, stream>>>(xz, xwl, cw, cb, part, ub);
        // dedicated split-K reduce (coalesced), then 3 scan kernels read dbc
        k_red8<<<LSEQ * 80 / 1024, 256, 0, stream>>>(part, dbc);
        k_scan1d<<<6 * NCHUNK, 256, 0, stream>>>(dbc, dtw, dtbb, ub, al, chunkS, sumdt);
        k_scan2p<<<EDIM * NDIM / 64, 256, 0, stream>>>(chunkS, sumdt, al, sInit);
        k_scan3d<<<6 * NCHUNK, 256, 0, stream>>>(dbc, dtw, dtbb, ub, xz, al, Dpl,
                                                 sInit, yzb);
        // out_proj: split-K=4 (Kh=384) -> hpart[4]; 768 blocks (3/CU)
        k_gemm_sk<bf16><<<dim3(12, 16, HSPLIT), 256, 0, stream>>>(yzb, EDIM, outw, EDIM, nullptr,
                                                                  hpart, HDIM, EDIM / HSPLIT, 0);
    }

    // head: A = sum of 4 fp32 partials, W fp32 converted in staging
    k_gemm_h<<<dim3(4, 16), 256, 0, stream>>>(hpart, HDIM, head_w, HDIM, head_b,
                                              out, SDIM, HDIM);
}

// Round 14
// 317.379 us; speedup vs baseline: 2.6618x; 1.0219x over previous
//
#include <hip/hip_runtime.h>
#include <hip/hip_bf16.h>
#include <math.h>

// Problem dims
#define SDIM 256
#define HDIM 768
#define EDIM 1536
#define NDIM 16
#define KCONV 4
#define RDIM 48
#define NLAYER 2
#define LSEQ 1024

#define NCHUNK 128
#define CHLEN (LSEQ / NCHUNK)   // 8
#define CPG (NCHUNK / 4)        // 32 chunks per prefix group
#define XSPLIT 24               // r14: 8->24 (XKCH=64) -> xproj 256->768 blocks (1->3/CU)
#define XKCH (EDIM / XSPLIT)    // 64
#define HSPLIT 4                // split-K for emb/out_proj (r13: +15us from 1.5->3 blk/CU)

typedef __hip_bfloat16 bf16;
typedef __attribute__((ext_vector_type(8))) short short8;
typedef __attribute__((ext_vector_type(4))) float f32x4;

__device__ __forceinline__ float softplusf(float x) {
    return (x > 20.f) ? x : log1pf(expf(x));
}
__device__ __forceinline__ float siluf(float x) {
    return x / (1.f + expf(-x));
}

// stage 8 elements into LDS as bf16 (bf16 source: raw copy; fp32 source: convert)
__device__ __forceinline__ void ld8(short* d, const bf16* s) {
    *(uint4*)d = *(const uint4*)s;
}
__device__ __forceinline__ void ld8(short* d, const float* s) {
    float4 a = *(const float4*)s;
    float4 b = *(const float4*)(s + 4);
    bf16 t[8] = {(bf16)a.x, (bf16)a.y, (bf16)a.z, (bf16)a.w,
                 (bf16)b.x, (bf16)b.y, (bf16)b.z, (bf16)b.w};
    *(uint4*)d = *(const uint4*)t;
}

// ---------------- MFMA bf16 GEMM 64x64 tile, split-K, fp32 partials (emb, out_proj) ----
template <typename AT>
__global__ __launch_bounds__(256) void k_gemm_sk(const AT* __restrict__ A, int lda,
                                                 const float* __restrict__ W, int ldw,
                                                 const float* __restrict__ bias,
                                                 float* __restrict__ part,
                                                 int N, int Kh, int useBias)
{
    __shared__ __align__(16) short As[64][72];
    __shared__ __align__(16) short Ws[64][72];

    const int tid  = threadIdx.x;
    const int lane = tid & 63, wid = tid >> 6;
    const int wm = wid >> 1, wn = wid & 1;
    const int row0 = blockIdx.y * 64, col0 = blockIdx.x * 64;
    const int quad = lane >> 4, l16 = lane & 15;
    const int kbase = blockIdx.z * Kh;

    f32x4 acc[2][2] = {};
    for (int k0 = 0; k0 < Kh; k0 += 64) {
        #pragma unroll
        for (int i = 0; i < 2; i++) {
            int id = tid + i * 256;
            int r = id >> 3, g = id & 7;
            ld8(&As[r][g * 8], A + (size_t)(row0 + r) * lda + kbase + k0 + g * 8);
            ld8(&Ws[r][g * 8], W + (size_t)(col0 + r) * ldw + kbase + k0 + g * 8);
        }
        __syncthreads();
        #pragma unroll
        for (int ks = 0; ks < 64; ks += 32) {
            short8 af[2], bfr[2];
            #pragma unroll
            for (int i = 0; i < 2; i++) af[i] = *(const short8*)&As[wm * 32 + i * 16 + l16][ks + quad * 8];
            #pragma unroll
            for (int j = 0; j < 2; j++) bfr[j] = *(const short8*)&Ws[wn * 32 + j * 16 + l16][ks + quad * 8];
            #pragma unroll
            for (int i = 0; i < 2; i++)
                #pragma unroll
                for (int j = 0; j < 2; j++)
                    acc[i][j] = __builtin_amdgcn_mfma_f32_16x16x32_bf16(af[i], bfr[j], acc[i][j], 0, 0, 0);
        }
        __syncthreads();
    }
    float* pdst = part + (size_t)blockIdx.z * LSEQ * N;
    #pragma unroll
    for (int i = 0; i < 2; i++) {
        #pragma unroll
        for (int j = 0; j < 2; j++) {
            int gn = col0 + wn * 32 + j * 16 + l16;
            int gm0 = row0 + wm * 32 + i * 16 + quad * 4;
            #pragma unroll
            for (int r = 0; r < 4; r++) {
                float v = acc[i][j][r];
                if (useBias && blockIdx.z == 0) v += bias[gn];
                pdst[(size_t)(gm0 + r) * N + gn] = v;
            }
        }
    }
}

// ---------------- in_proj GEMM: no split-K, writes bf16 xz directly ----------------
__global__ __launch_bounds__(256) void k_gemm_skb(const bf16* __restrict__ A, int lda,
                                                  const float* __restrict__ W, int ldw,
                                                  bf16* __restrict__ outp,
                                                  int N, int Kh)
{
    __shared__ __align__(16) short As[64][72];
    __shared__ __align__(16) short Ws[64][72];

    const int tid  = threadIdx.x;
    const int lane = tid & 63, wid = tid >> 6;
    const int wm = wid >> 1, wn = wid & 1;
    const int row0 = blockIdx.y * 64, col0 = blockIdx.x * 64;
    const int quad = lane >> 4, l16 = lane & 15;

    f32x4 acc[2][2] = {};
    for (int k0 = 0; k0 < Kh; k0 += 64) {
        #pragma unroll
        for (int i = 0; i < 2; i++) {
            int id = tid + i * 256;
            int r = id >> 3, g = id & 7;
            ld8(&As[r][g * 8], A + (size_t)(row0 + r) * lda + k0 + g * 8);
            ld8(&Ws[r][g * 8], W + (size_t)(col0 + r) * ldw + k0 + g * 8);
        }
        __syncthreads();
        #pragma unroll
        for (int ks = 0; ks < 64; ks += 32) {
            short8 af[2], bfr[2];
            #pragma unroll
            for (int i = 0; i < 2; i++) af[i] = *(const short8*)&As[wm * 32 + i * 16 + l16][ks + quad * 8];
            #pragma unroll
            for (int j = 0; j < 2; j++) bfr[j] = *(const short8*)&Ws[wn * 32 + j * 16 + l16][ks + quad * 8];
            #pragma unroll
            for (int i = 0; i < 2; i++)
                #pragma unroll
                for (int j = 0; j < 2; j++)
                    acc[i][j] = __builtin_amdgcn_mfma_f32_16x16x32_bf16(af[i], bfr[j], acc[i][j], 0, 0, 0);
        }
        __syncthreads();
    }
    #pragma unroll
    for (int i = 0; i < 2; i++) {
        #pragma unroll
        for (int j = 0; j < 2; j++) {
            int gn = col0 + wn * 32 + j * 16 + l16;
            int gm0 = row0 + wm * 32 + i * 16 + quad * 4;
            #pragma unroll
            for (int r = 0; r < 4; r++)
                outp[(size_t)(gm0 + r) * N + gn] = (bf16)acc[i][j][r];
        }
    }
}

// ---------------- head GEMM: A = sum of 4 fp32 partials, W fp32 ----------------
__global__ __launch_bounds__(256) void k_gemm_h(const float* __restrict__ hp, int lda,
                                                const float* __restrict__ W, int ldw,
                                                const float* __restrict__ bias,
                                                float* __restrict__ out, int N, int Kd)
{
    __shared__ __align__(16) short As[64][72];
    __shared__ __align__(16) short Ws[64][72];

    const int tid  = threadIdx.x;
    const int lane = tid & 63, wid = tid >> 6;
    const int wm = wid >> 1, wn = wid & 1;
    const int row0 = blockIdx.y * 64, col0 = blockIdx.x * 64;
    const int quad = lane >> 4, l16 = lane & 15;
    const size_t LH = (size_t)LSEQ * HDIM;

    f32x4 acc[2][2] = {};
    for (int k0 = 0; k0 < Kd; k0 += 64) {
        #pragma unroll
        for (int i = 0; i < 2; i++) {
            int id = tid + i * 256;
            int r = id >> 3, g = id & 7;
            size_t base = (size_t)(row0 + r) * lda + k0 + g * 8;
            float4 a0 = *(const float4*)(hp + base);
            float4 a1 = *(const float4*)(hp + LH + base);
            float4 a2 = *(const float4*)(hp + 2 * LH + base);
            float4 a3 = *(const float4*)(hp + 3 * LH + base);
            float4 b0 = *(const float4*)(hp + base + 4);
            float4 b1 = *(const float4*)(hp + LH + base + 4);
            float4 b2 = *(const float4*)(hp + 2 * LH + base + 4);
            float4 b3 = *(const float4*)(hp + 3 * LH + base + 4);
            bf16 tmp[8] = {(bf16)(a0.x + a1.x + a2.x + a3.x), (bf16)(a0.y + a1.y + a2.y + a3.y),
                           (bf16)(a0.z + a1.z + a2.z + a3.z), (bf16)(a0.w + a1.w + a2.w + a3.w),
                           (bf16)(b0.x + b1.x + b2.x + b3.x), (bf16)(b0.y + b1.y + b2.y + b3.y),
                           (bf16)(b0.z + b1.z + b2.z + b3.z), (bf16)(b0.w + b1.w + b2.w + b3.w)};
            *(uint4*)&As[r][g * 8] = *(const uint4*)tmp;
            ld8(&Ws[r][g * 8], W + (size_t)(col0 + r) * ldw + k0 + g * 8);
        }
        __syncthreads();
        #pragma unroll
        for (int ks = 0; ks < 64; ks += 32) {
            short8 af[2], bfr[2];
            #pragma unroll
            for (int i = 0; i < 2; i++) af[i] = *(const short8*)&As[wm * 32 + i * 16 + l16][ks + quad * 8];
            #pragma unroll
            for (int j = 0; j < 2; j++) bfr[j] = *(const short8*)&Ws[wn * 32 + j * 16 + l16][ks + quad * 8];
            #pragma unroll
            for (int i = 0; i < 2; i++)
                #pragma unroll
                for (int j = 0; j < 2; j++)
                    acc[i][j] = __builtin_amdgcn_mfma_f32_16x16x32_bf16(af[i], bfr[j], acc[i][j], 0, 0, 0);
        }
        __syncthreads();
    }
    #pragma unroll
    for (int i = 0; i < 2; i++) {
        #pragma unroll
        for (int j = 0; j < 2; j++) {
            int gn = col0 + wn * 32 + j * 16 + l16;
            int gm0 = row0 + wm * 32 + i * 16 + quad * 4;
            #pragma unroll
            for (int r = 0; r < 4; r++)
                out[(size_t)(gm0 + r) * N + gn] = acc[i][j][r] + bias[gn];
        }
    }
}

// ---------------- xproj GEMM with fused causal-conv+silu A-staging ----------------
// XSPLIT=24 -> XKCH=64: one K-iteration per block, 768 blocks (3/CU). Total Xr/W
// staging traffic invariant vs XSPLIT=8 (16x24 tile-loads either way).
__global__ __launch_bounds__(256) void k_xproj_conv(
    const bf16* __restrict__ xz,
    const float* __restrict__ W,     // x_proj fp32 [80][EDIM]
    const float* __restrict__ cw,    // [EDIM][4]
    const float* __restrict__ cb,    // [EDIM]
    float* __restrict__ part,
    bf16* __restrict__ ub)
{
    __shared__ __align__(16) short As[64][72];
    __shared__ __align__(16) short Ws[64][72];
    __shared__ __align__(16) bf16 Xr[67][64];

    const int tid  = threadIdx.x;
    const int lane = tid & 63, wid = tid >> 6;
    const int wm = wid >> 1, wn = wid & 1;
    const int row0 = blockIdx.y * 64, col0 = blockIdx.x * 64;
    const int quad = lane >> 4, l16 = lane & 15;
    const int kbase = blockIdx.z * XKCH;

    f32x4 acc[2][2] = {};
    for (int k0 = 0; k0 < XKCH; k0 += 64) {
        const int ecol = kbase + k0;
        for (int idx = tid; idx < 67 * 8; idx += 256) {
            int r = idx >> 3, g = idx & 7;
            int gr = row0 - 3 + r;
            uint4 v = {0, 0, 0, 0};
            if (gr >= 0) v = *(const uint4*)(xz + (size_t)gr * (2 * EDIM) + ecol + g * 8);
            *(uint4*)&Xr[r][g * 8] = v;
        }
        #pragma unroll
        for (int i = 0; i < 2; i++) {
            int id = tid + i * 256;
            int r = id >> 3, g = id & 7;
            if (col0 + r < 80) {
                ld8(&Ws[r][g * 8], W + (size_t)(col0 + r) * EDIM + ecol + g * 8);
            } else {
                uint4 z = {0, 0, 0, 0};
                *(uint4*)&Ws[r][g * 8] = z;
            }
        }
        __syncthreads();
        {
            const int e = tid & 63;
            const int rb = (tid >> 6) * 16;
            const float cw0 = cw[(ecol + e) * 4 + 0];
            const float cw1 = cw[(ecol + e) * 4 + 1];
            const float cw2 = cw[(ecol + e) * 4 + 2];
            const float cw3 = cw[(ecol + e) * 4 + 3];
            const float cbv = cb[ecol + e];
            #pragma unroll
            for (int j = 0; j < 16; j++) {
                int r = rb + j;
                float s = cbv
                        + cw0 * (float)Xr[r + 0][e]
                        + cw1 * (float)Xr[r + 1][e]
                        + cw2 * (float)Xr[r + 2][e]
                        + cw3 * (float)Xr[r + 3][e];
                bf16 h = (bf16)siluf(s);
                As[r][e] = *reinterpret_cast<short*>(&h);
            }
        }
        __syncthreads();
        if (blockIdx.x == 0) {
            for (int idx = tid; idx < 64 * 8; idx += 256) {
                int r = idx >> 3, g = idx & 7;
                *(uint4*)(ub + (size_t)(row0 + r) * EDIM + ecol + g * 8) = *(const uint4*)&As[r][g * 8];
            }
        }
        #pragma unroll
        for (int ks = 0; ks < 64; ks += 32) {
            short8 af[2], bfr[2];
            #pragma unroll
            for (int i = 0; i < 2; i++) af[i] = *(const short8*)&As[wm * 32 + i * 16 + l16][ks + quad * 8];
            #pragma unroll
            for (int j = 0; j < 2; j++) bfr[j] = *(const short8*)&Ws[wn * 32 + j * 16 + l16][ks + quad * 8];
            #pragma unroll
            for (int i = 0; i < 2; i++)
                #pragma unroll
                for (int j = 0; j < 2; j++)
                    acc[i][j] = __builtin_amdgcn_mfma_f32_16x16x32_bf16(af[i], bfr[j], acc[i][j], 0, 0, 0);
        }
        __syncthreads();
    }

    float* pdst = part + (size_t)blockIdx.z * (LSEQ * 80);
    #pragma unroll
    for (int i = 0; i < 2; i++) {
        #pragma unroll
        for (int j = 0; j < 2; j++) {
            int gn = col0 + wn * 32 + j * 16 + l16;
            int gm0 = row0 + wm * 32 + i * 16 + quad * 4;
            if (gn < 80) {
                #pragma unroll
                for (int r = 0; r < 4; r++)
                    pdst[(size_t)(gm0 + r) * 80 + gn] = acc[i][j][r];
            }
        }
    }
}

// ---------------- split-K reduce: part[XSPLIT][LSEQ][80] -> dbc[LSEQ][80] ------------
__global__ __launch_bounds__(256) void k_red8(const float* __restrict__ part,
                                              float* __restrict__ dbc)
{
    const int i = (blockIdx.x * 256 + threadIdx.x) * 4;
    float4 s = *(const float4*)(part + i);
    #pragma unroll
    for (int p = 1; p < XSPLIT; p++) {
        float4 v = *(const float4*)(part + (size_t)p * (LSEQ * 80) + i);
        s.x += v.x; s.y += v.y; s.z += v.z; s.w += v.w;
    }
    *(float4*)(dbc + i) = s;
}

// ---------------- residual + rmsnorm (sums HSPLIT=4 partials) ----------------
__global__ __launch_bounds__(256) void k_rms(const float* __restrict__ hp,
                                             float* __restrict__ res,
                                             bf16* __restrict__ hnb, const float* __restrict__ w,
                                             int first)
{
    __shared__ float red[4];
    __shared__ float tot;
    const int tid = threadIdx.x;
    const int t = blockIdx.x;
    const size_t LH = (size_t)LSEQ * HDIM;
    float v[3]; float ss = 0.f;
    #pragma unroll
    for (int r = 0; r < 3; r++) {
        int j = tid + r * 256;
        size_t o = (size_t)t * HDIM + j;
        float xv = hp[o] + hp[LH + o] + hp[2 * LH + o] + hp[3 * LH + o];
        if (!first) xv += res[o];
        v[r] = xv;
        res[o] = xv;
        ss += xv * xv;
    }
    #pragma unroll
    for (int m = 32; m >= 1; m >>= 1) ss += __shfl_down(ss, m);
    int wid = tid >> 6;
    if ((tid & 63) == 0) red[wid] = ss;
    __syncthreads();
    if (tid == 0) tot = red[0] + red[1] + red[2] + red[3];
    __syncthreads();
    float scale = rsqrtf(tot / (float)HDIM + 1e-5f);
    #pragma unroll
    for (int r = 0; r < 3; r++) {
        int j = tid + r * 256;
        hnb[(size_t)t * HDIM + j] = (bf16)(v[r] * scale * w[j]);
    }
}

// ---------------- shared helper: per-block dt/B/C tile from reduced dbc ----------
__device__ __forceinline__ void dt_tile(
    const float* __restrict__ dbc, const float* __restrict__ dtw,
    const float* __restrict__ dtbb,
    float (*A_red)[48], float (*BC)[32], float (*dtL)[256],
    int t0, int e, int tid)
{
    for (int idx = tid; idx < CHLEN * 80; idx += 256) {
        int tt = idx / 80, k = idx - tt * 80;
        float v = dbc[(size_t)(t0 + tt) * 80 + k];
        if (k < RDIM) A_red[tt][k] = v; else BC[tt][k - RDIM] = v;
    }
    __syncthreads();
    const float* we = dtw + (size_t)e * RDIM;
    const float bb = dtbb[e];
    float acc[CHLEN] = {};
    #pragma unroll 3
    for (int k = 0; k < RDIM; k += 4) {
        float4 w4 = *(const float4*)(we + k);
        #pragma unroll
        for (int j = 0; j < CHLEN; j++) {
            float4 a4 = *(const float4*)&A_red[j][k];
            acc[j] += a4.x * w4.x + a4.y * w4.y + a4.z * w4.z + a4.w * w4.w;
        }
    }
    #pragma unroll
    for (int j = 0; j < CHLEN; j++)
        dtL[j][tid] = softplusf(acc[j] + bb);
}

// ---------------- scan1: dt-GEMM + per-chunk local scan ----------------
__global__ __launch_bounds__(256) void k_scan1d(
    const float* __restrict__ dbc, const float* __restrict__ dtw,
    const float* __restrict__ dtbb,
    const bf16*  __restrict__ ub,
    const float* __restrict__ a_log,
    float* __restrict__ chunkS, float* __restrict__ sumdt)
{
    __shared__ __align__(16) float A_red[CHLEN][48];
    __shared__ __align__(16) float BC[CHLEN][32];
    __shared__ __align__(16) float dtL[CHLEN][256];
    const int tid = threadIdx.x;
    const int ex = blockIdx.x % 6, c = blockIdx.x / 6;
    const int e = ex * 256 + tid;
    const int t0 = c * CHLEN;

    dt_tile(dbc, dtw, dtbb, A_red, BC, dtL, t0, e, tid);

    // prefetch u for the whole chunk (independent loads, batched issue)
    float u8[CHLEN];
    #pragma unroll
    for (int tt = 0; tt < CHLEN; tt++)
        u8[tt] = (float)ub[(size_t)(t0 + tt) * EDIM + e];

    float A[16];
    #pragma unroll
    for (int q = 0; q < 4; q++) {
        float4 a4 = *(const float4*)(a_log + (size_t)e * NDIM + q * 4);
        A[q*4+0] = -__expf(a4.x); A[q*4+1] = -__expf(a4.y);
        A[q*4+2] = -__expf(a4.z); A[q*4+3] = -__expf(a4.w);
    }
    float s[16] = {};
    float sd = 0.f;
    #pragma unroll
    for (int tt = 0; tt < CHLEN; tt++) {
        float dtv = dtL[tt][tid];
        float dtu = dtv * u8[tt];
        sd += dtv;
        #pragma unroll
        for (int n = 0; n < 16; n++) s[n] = s[n] * __expf(dtv * A[n]) + dtu * BC[tt][n];
    }
    float* cs = chunkS + ((size_t)c * EDIM + e) * NDIM;
    #pragma unroll
    for (int q = 0; q < 4; q++)
        *(float4*)(cs + q * 4) = make_float4(s[q*4+0], s[q*4+1], s[q*4+2], s[q*4+3]);
    sumdt[(size_t)c * EDIM + e] = sd;
}

// ---------------- scan2: two-level affine prefix over chunks -> sInit ----------------
__global__ __launch_bounds__(256) void k_scan2p(
    const float* __restrict__ chunkS, const float* __restrict__ sumdt,
    const float* __restrict__ a_log, float* __restrict__ sInit)
{
    __shared__ float sP[256];
    __shared__ float sX[256];
    const int tid = threadIdx.x;
    const int pl = tid & 63, q = tid >> 6;
    const int p = blockIdx.x * 64 + pl;   // pair index = e*16+n
    const int pe = p >> 4;
    const float Aen = -__expf(a_log[p]);
    float P[CPG], X[CPG];
    float Pc = 1.f, Xc = 0.f;
    #pragma unroll
    for (int j = 0; j < CPG; j++) {
        int cc = q * CPG + j;
        float Pj = __expf(Aen * sumdt[(size_t)cc * EDIM + pe]);
        float Xj = chunkS[(size_t)cc * (EDIM * NDIM) + p];
        P[j] = Pj; X[j] = Xj;
        Xc = Pj * Xc + Xj;
        Pc *= Pj;
    }
    sP[q * 64 + pl] = Pc;
    sX[q * 64 + pl] = Xc;
    __syncthreads();
    float s = 0.f;
    for (int g = 0; g < q; g++) s = sP[g * 64 + pl] * s + sX[g * 64 + pl];
    #pragma unroll
    for (int j = 0; j < CPG; j++) {
        int cc = q * CPG + j;
        sInit[(size_t)cc * (EDIM * NDIM) + p] = s;
        s = P[j] * s + X[j];
    }
}

// ---------------- scan3: dt-GEMM + final scan with carry + y/z gating ----------
__global__ __launch_bounds__(256) void k_scan3d(
    const float* __restrict__ dbc, const float* __restrict__ dtw,
    const float* __restrict__ dtbb,
    const bf16*  __restrict__ ub,
    const bf16*  __restrict__ xz,
    const float* __restrict__ a_log,
    const float* __restrict__ Dp,
    const float* __restrict__ sInit,
    bf16* __restrict__ yzb)
{
    __shared__ __align__(16) float A_red[CHLEN][48];
    __shared__ __align__(16) float BC[CHLEN][32];
    __shared__ __align__(16) float dtL[CHLEN][256];
    const int tid = threadIdx.x;
    const int ex = blockIdx.x % 6, c = blockIdx.x / 6;
    const int e = ex * 256 + tid;
    const int t0 = c * CHLEN;

    dt_tile(dbc, dtw, dtbb, A_red, BC, dtL, t0, e, tid);

    // prefetch u and z for the whole chunk (independent loads, batched issue)
    float u8[CHLEN], z8[CHLEN];
    #pragma unroll
    for (int tt = 0; tt < CHLEN; tt++) {
        u8[tt] = (float)ub[(size_t)(t0 + tt) * EDIM + e];
        z8[tt] = (float)xz[(size_t)(t0 + tt) * (2 * EDIM) + EDIM + e];
    }

    float A[16];
    #pragma unroll
    for (int q = 0; q < 4; q++) {
        float4 a4 = *(const float4*)(a_log + (size_t)e * NDIM + q * 4);
        A[q*4+0] = -__expf(a4.x); A[q*4+1] = -__expf(a4.y);
        A[q*4+2] = -__expf(a4.z); A[q*4+3] = -__expf(a4.w);
    }
    const float dv = Dp[e];
    float s[16];
    const float* si = sInit + ((size_t)c * EDIM + e) * NDIM;
    #pragma unroll
    for (int q = 0; q < 4; q++) {
        float4 s4 = *(const float4*)(si + q * 4);
        s[q*4+0] = s4.x; s[q*4+1] = s4.y; s[q*4+2] = s4.z; s[q*4+3] = s4.w;
    }
    #pragma unroll
    for (int tt = 0; tt < CHLEN; tt++) {
        float dtv = dtL[tt][tid];
        float uv  = u8[tt];
        float dtu = dtv * uv;
        float y = 0.f;
        #pragma unroll
        for (int n = 0; n < 16; n++) {
            s[n] = s[n] * __expf(dtv * A[n]) + dtu * BC[tt][n];
            y += s[n] * BC[tt][16 + n];
        }
        y += uv * dv;
        yzb[(size_t)(t0 + tt) * EDIM + e] = (bf16)(y * siluf(z8[tt]));
    }
}

extern "C" void kernel_launch(void* const* d_in, const int* in_sizes, int n_in,
                              void* d_out, int out_size, void* d_ws, size_t ws_size,
                              hipStream_t stream)
{
    const float* x        = (const float*)d_in[0];
    const float* emb_w    = (const float*)d_in[1];
    const float* emb_b    = (const float*)d_in[2];
    const float* norm_w   = (const float*)d_in[3];
    const float* in_proj  = (const float*)d_in[4];
    const float* conv_w   = (const float*)d_in[5];
    const float* conv_b   = (const float*)d_in[6];
    const float* x_proj   = (const float*)d_in[7];
    const float* dt_w     = (const float*)d_in[8];
    const float* dt_b     = (const float*)d_in[9];
    const float* A_log    = (const float*)d_in[10];
    const float* Dp       = (const float*)d_in[11];
    const float* out_proj = (const float*)d_in[12];
    const float* head_w   = (const float*)d_in[13];
    const float* head_b   = (const float*)d_in[14];
    float* out = (float*)d_out;

    float* ws = (float*)d_ws;
    size_t off = 0;
    float* hpart  = ws + off; off += (size_t)HSPLIT * LSEQ * HDIM;
    float* res    = ws + off; off += (size_t)LSEQ * HDIM;
    float* part   = ws + off; off += (size_t)XSPLIT * LSEQ * 80;
    float* dbc    = ws + off; off += (size_t)LSEQ * 80;
    float* chunkS = ws + off; off += (size_t)NCHUNK * EDIM * NDIM;
    float* sumdt  = ws + off; off += (size_t)NCHUNK * EDIM;
    float* sInit  = ws + off; off += (size_t)NCHUNK * EDIM * NDIM;
    bf16* xz      = (bf16*)(ws + off); off += (size_t)LSEQ * 2 * EDIM / 2;
    bf16* hnb     = (bf16*)(ws + off); off += (size_t)LSEQ * HDIM / 2;
    bf16* yzb     = (bf16*)(ws + off); off += (size_t)LSEQ * EDIM / 2;
    bf16* ub      = (bf16*)(ws + off); off += (size_t)LSEQ * EDIM / 2;

    // embed: split-K=4 (Kh=64) -> hpart[4]; 768 blocks (3/CU)
    k_gemm_sk<float><<<dim3(12, 16, HSPLIT), 256, 0, stream>>>(x, SDIM, emb_w, SDIM, emb_b,
                                                               hpart, HDIM, SDIM / HSPLIT, 1);

    for (int l = 0; l < NLAYER; l++) {
        const float* inw  = in_proj  + (size_t)l * 2 * EDIM * HDIM;
        const float* outw = out_proj + (size_t)l * HDIM * EDIM;
        const float* xwl  = x_proj   + (size_t)l * 80 * EDIM;
        const float* cw   = conv_w   + (size_t)l * EDIM * KCONV;
        const float* cb   = conv_b   + (size_t)l * EDIM;
        const float* dtw  = dt_w     + (size_t)l * EDIM * RDIM;
        const float* dtbb = dt_b     + (size_t)l * EDIM;
        const float* al   = A_log    + (size_t)l * EDIM * NDIM;
        const float* Dpl  = Dp       + (size_t)l * EDIM;

        k_rms<<<LSEQ, 256, 0, stream>>>(hpart, res, hnb, norm_w + (size_t)l * HDIM, l == 0);
        // in_proj: full-K (768), 64x64 tile, single bf16 xz output; 768 blocks
        k_gemm_skb<<<dim3(48, 16, 1), 256, 0, stream>>>(hnb, HDIM, inw, HDIM,
                                                        xz, 2 * EDIM, HDIM);
        // xproj with fused conv+silu; XSPLIT=24 -> 768 blocks (3/CU)
        k_xproj_conv<<<dim3(2, 16, XSPLIT), 256, 0, stream>>>(xz, xwl, cw, cb, part, ub);
        // dedicated split-K reduce (coalesced), then 3 scan kernels read dbc
        k_red8<<<LSEQ * 80 / 1024, 256, 0, stream>>>(part, dbc);
        k_scan1d<<<6 * NCHUNK, 256, 0, stream>>>(dbc, dtw, dtbb, ub, al, chunkS, sumdt);
        k_scan2p<<<EDIM * NDIM / 64, 256, 0, stream>>>(chunkS, sumdt, al, sInit);
        k_scan3d<<<6 * NCHUNK, 256, 0, stream>>>(dbc, dtw, dtbb, ub, xz, al, Dpl,
                                                 sInit, yzb);
        // out_proj: split-K=4 (Kh=384) -> hpart[4]; 768 blocks (3/CU)
        k_gemm_sk<bf16><<<dim3(12, 16, HSPLIT), 256, 0, stream>>>(yzb, EDIM, outw, EDIM, nullptr,
                                                                  hpart, HDIM, EDIM / HSPLIT, 0);
    }

    // head: A = sum of 4 fp32 partials, W fp32 converted in staging
    k_gemm_h<<<dim3(4, 16), 256, 0, stream>>>(hpart, HDIM, head_w, HDIM, head_b,
                                              out, SDIM, HDIM);
}

// Round 15
// 306.206 us; speedup vs baseline: 2.7590x; 1.0365x over previous
//
#include <hip/hip_runtime.h>
#include <hip/hip_bf16.h>
#include <math.h>

// Problem dims
#define SDIM 256
#define HDIM 768
#define EDIM 1536
#define NDIM 16
#define KCONV 4
#define RDIM 48
#define NLAYER 2
#define LSEQ 1024

#define NCHUNK 128
#define CHLEN (LSEQ / NCHUNK)   // 8
#define CPG (NCHUNK / 4)        // 32 chunks per prefix group
#define XSPLIT 24               // xproj split-K (r14: 256->768 blocks, -7us)
#define XKCH (EDIM / XSPLIT)    // 64
#define HSPLIT 4                // emb/out_proj split-K (r13: -15us)
#define ISPLIT 2                // in_proj split-K (r15: 768->1536 blocks, 6 K-iters)

typedef __hip_bfloat16 bf16;
typedef __attribute__((ext_vector_type(8))) short short8;
typedef __attribute__((ext_vector_type(4))) float f32x4;

__device__ __forceinline__ float softplusf(float x) {
    return (x > 20.f) ? x : log1pf(expf(x));
}
__device__ __forceinline__ float siluf(float x) {
    return x / (1.f + expf(-x));
}

// stage 8 elements into LDS as bf16 (bf16 source: raw copy; fp32 source: convert)
__device__ __forceinline__ void ld8(short* d, const bf16* s) {
    *(uint4*)d = *(const uint4*)s;
}
__device__ __forceinline__ void ld8(short* d, const float* s) {
    float4 a = *(const float4*)s;
    float4 b = *(const float4*)(s + 4);
    bf16 t[8] = {(bf16)a.x, (bf16)a.y, (bf16)a.z, (bf16)a.w,
                 (bf16)b.x, (bf16)b.y, (bf16)b.z, (bf16)b.w};
    *(uint4*)d = *(const uint4*)t;
}

// ---------------- MFMA bf16 GEMM 64x64 tile, split-K, fp32 partials (emb, out_proj) ----
template <typename AT>
__global__ __launch_bounds__(256) void k_gemm_sk(const AT* __restrict__ A, int lda,
                                                 const float* __restrict__ W, int ldw,
                                                 const float* __restrict__ bias,
                                                 float* __restrict__ part,
                                                 int N, int Kh, int useBias)
{
    __shared__ __align__(16) short As[64][72];
    __shared__ __align__(16) short Ws[64][72];

    const int tid  = threadIdx.x;
    const int lane = tid & 63, wid = tid >> 6;
    const int wm = wid >> 1, wn = wid & 1;
    const int row0 = blockIdx.y * 64, col0 = blockIdx.x * 64;
    const int quad = lane >> 4, l16 = lane & 15;
    const int kbase = blockIdx.z * Kh;

    f32x4 acc[2][2] = {};
    for (int k0 = 0; k0 < Kh; k0 += 64) {
        #pragma unroll
        for (int i = 0; i < 2; i++) {
            int id = tid + i * 256;
            int r = id >> 3, g = id & 7;
            ld8(&As[r][g * 8], A + (size_t)(row0 + r) * lda + kbase + k0 + g * 8);
            ld8(&Ws[r][g * 8], W + (size_t)(col0 + r) * ldw + kbase + k0 + g * 8);
        }
        __syncthreads();
        #pragma unroll
        for (int ks = 0; ks < 64; ks += 32) {
            short8 af[2], bfr[2];
            #pragma unroll
            for (int i = 0; i < 2; i++) af[i] = *(const short8*)&As[wm * 32 + i * 16 + l16][ks + quad * 8];
            #pragma unroll
            for (int j = 0; j < 2; j++) bfr[j] = *(const short8*)&Ws[wn * 32 + j * 16 + l16][ks + quad * 8];
            #pragma unroll
            for (int i = 0; i < 2; i++)
                #pragma unroll
                for (int j = 0; j < 2; j++)
                    acc[i][j] = __builtin_amdgcn_mfma_f32_16x16x32_bf16(af[i], bfr[j], acc[i][j], 0, 0, 0);
        }
        __syncthreads();
    }
    float* pdst = part + (size_t)blockIdx.z * LSEQ * N;
    #pragma unroll
    for (int i = 0; i < 2; i++) {
        #pragma unroll
        for (int j = 0; j < 2; j++) {
            int gn = col0 + wn * 32 + j * 16 + l16;
            int gm0 = row0 + wm * 32 + i * 16 + quad * 4;
            #pragma unroll
            for (int r = 0; r < 4; r++) {
                float v = acc[i][j][r];
                if (useBias && blockIdx.z == 0) v += bias[gn];
                pdst[(size_t)(gm0 + r) * N + gn] = v;
            }
        }
    }
}

// ---------------- in_proj GEMM: split-K=2, bf16 partials (consumers add) ----------
__global__ __launch_bounds__(256) void k_gemm_skb(const bf16* __restrict__ A, int lda,
                                                  const float* __restrict__ W, int ldw,
                                                  bf16* __restrict__ outp,
                                                  int N, int Kh)
{
    __shared__ __align__(16) short As[64][72];
    __shared__ __align__(16) short Ws[64][72];

    const int tid  = threadIdx.x;
    const int lane = tid & 63, wid = tid >> 6;
    const int wm = wid >> 1, wn = wid & 1;
    const int row0 = blockIdx.y * 64, col0 = blockIdx.x * 64;
    const int quad = lane >> 4, l16 = lane & 15;
    const int kbase = blockIdx.z * Kh;

    f32x4 acc[2][2] = {};
    for (int k0 = 0; k0 < Kh; k0 += 64) {
        #pragma unroll
        for (int i = 0; i < 2; i++) {
            int id = tid + i * 256;
            int r = id >> 3, g = id & 7;
            ld8(&As[r][g * 8], A + (size_t)(row0 + r) * lda + kbase + k0 + g * 8);
            ld8(&Ws[r][g * 8], W + (size_t)(col0 + r) * ldw + kbase + k0 + g * 8);
        }
        __syncthreads();
        #pragma unroll
        for (int ks = 0; ks < 64; ks += 32) {
            short8 af[2], bfr[2];
            #pragma unroll
            for (int i = 0; i < 2; i++) af[i] = *(const short8*)&As[wm * 32 + i * 16 + l16][ks + quad * 8];
            #pragma unroll
            for (int j = 0; j < 2; j++) bfr[j] = *(const short8*)&Ws[wn * 32 + j * 16 + l16][ks + quad * 8];
            #pragma unroll
            for (int i = 0; i < 2; i++)
                #pragma unroll
                for (int j = 0; j < 2; j++)
                    acc[i][j] = __builtin_amdgcn_mfma_f32_16x16x32_bf16(af[i], bfr[j], acc[i][j], 0, 0, 0);
        }
        __syncthreads();
    }
    bf16* pdst = outp + (size_t)blockIdx.z * LSEQ * N;
    #pragma unroll
    for (int i = 0; i < 2; i++) {
        #pragma unroll
        for (int j = 0; j < 2; j++) {
            int gn = col0 + wn * 32 + j * 16 + l16;
            int gm0 = row0 + wm * 32 + i * 16 + quad * 4;
            #pragma unroll
            for (int r = 0; r < 4; r++)
                pdst[(size_t)(gm0 + r) * N + gn] = (bf16)acc[i][j][r];
        }
    }
}

// ---------------- head GEMM: A = sum of 4 fp32 partials, W fp32 ----------------
__global__ __launch_bounds__(256) void k_gemm_h(const float* __restrict__ hp, int lda,
                                                const float* __restrict__ W, int ldw,
                                                const float* __restrict__ bias,
                                                float* __restrict__ out, int N, int Kd)
{
    __shared__ __align__(16) short As[64][72];
    __shared__ __align__(16) short Ws[64][72];

    const int tid  = threadIdx.x;
    const int lane = tid & 63, wid = tid >> 6;
    const int wm = wid >> 1, wn = wid & 1;
    const int row0 = blockIdx.y * 64, col0 = blockIdx.x * 64;
    const int quad = lane >> 4, l16 = lane & 15;
    const size_t LH = (size_t)LSEQ * HDIM;

    f32x4 acc[2][2] = {};
    for (int k0 = 0; k0 < Kd; k0 += 64) {
        #pragma unroll
        for (int i = 0; i < 2; i++) {
            int id = tid + i * 256;
            int r = id >> 3, g = id & 7;
            size_t base = (size_t)(row0 + r) * lda + k0 + g * 8;
            float4 a0 = *(const float4*)(hp + base);
            float4 a1 = *(const float4*)(hp + LH + base);
            float4 a2 = *(const float4*)(hp + 2 * LH + base);
            float4 a3 = *(const float4*)(hp + 3 * LH + base);
            float4 b0 = *(const float4*)(hp + base + 4);
            float4 b1 = *(const float4*)(hp + LH + base + 4);
            float4 b2 = *(const float4*)(hp + 2 * LH + base + 4);
            float4 b3 = *(const float4*)(hp + 3 * LH + base + 4);
            bf16 tmp[8] = {(bf16)(a0.x + a1.x + a2.x + a3.x), (bf16)(a0.y + a1.y + a2.y + a3.y),
                           (bf16)(a0.z + a1.z + a2.z + a3.z), (bf16)(a0.w + a1.w + a2.w + a3.w),
                           (bf16)(b0.x + b1.x + b2.x + b3.x), (bf16)(b0.y + b1.y + b2.y + b3.y),
                           (bf16)(b0.z + b1.z + b2.z + b3.z), (bf16)(b0.w + b1.w + b2.w + b3.w)};
            *(uint4*)&As[r][g * 8] = *(const uint4*)tmp;
            ld8(&Ws[r][g * 8], W + (size_t)(col0 + r) * ldw + k0 + g * 8);
        }
        __syncthreads();
        #pragma unroll
        for (int ks = 0; ks < 64; ks += 32) {
            short8 af[2], bfr[2];
            #pragma unroll
            for (int i = 0; i < 2; i++) af[i] = *(const short8*)&As[wm * 32 + i * 16 + l16][ks + quad * 8];
            #pragma unroll
            for (int j = 0; j < 2; j++) bfr[j] = *(const short8*)&Ws[wn * 32 + j * 16 + l16][ks + quad * 8];
            #pragma unroll
            for (int i = 0; i < 2; i++)
                #pragma unroll
                for (int j = 0; j < 2; j++)
                    acc[i][j] = __builtin_amdgcn_mfma_f32_16x16x32_bf16(af[i], bfr[j], acc[i][j], 0, 0, 0);
        }
        __syncthreads();
    }
    #pragma unroll
    for (int i = 0; i < 2; i++) {
        #pragma unroll
        for (int j = 0; j < 2; j++) {
            int gn = col0 + wn * 32 + j * 16 + l16;
            int gm0 = row0 + wm * 32 + i * 16 + quad * 4;
            #pragma unroll
            for (int r = 0; r < 4; r++)
                out[(size_t)(gm0 + r) * N + gn] = acc[i][j][r] + bias[gn];
        }
    }
}

// ---------------- xproj GEMM with fused causal-conv+silu A-staging ----------------
// xz comes as 2 bf16 partials; Xr staging adds them (fp32 add, round to bf16 —
// round-0-verified numerics path).
__global__ __launch_bounds__(256) void k_xproj_conv(
    const bf16* __restrict__ xzp0,
    const bf16* __restrict__ xzp1,
    const float* __restrict__ W,     // x_proj fp32 [80][EDIM]
    const float* __restrict__ cw,    // [EDIM][4]
    const float* __restrict__ cb,    // [EDIM]
    float* __restrict__ part,
    bf16* __restrict__ ub)
{
    __shared__ __align__(16) short As[64][72];
    __shared__ __align__(16) short Ws[64][72];
    __shared__ __align__(16) bf16 Xr[67][64];

    const int tid  = threadIdx.x;
    const int lane = tid & 63, wid = tid >> 6;
    const int wm = wid >> 1, wn = wid & 1;
    const int row0 = blockIdx.y * 64, col0 = blockIdx.x * 64;
    const int quad = lane >> 4, l16 = lane & 15;
    const int kbase = blockIdx.z * XKCH;

    f32x4 acc[2][2] = {};
    for (int k0 = 0; k0 < XKCH; k0 += 64) {
        const int ecol = kbase + k0;
        for (int idx = tid; idx < 67 * 8; idx += 256) {
            int r = idx >> 3, g = idx & 7;
            int gr = row0 - 3 + r;
            uint4 v = {0, 0, 0, 0};
            if (gr >= 0) {
                size_t o = (size_t)gr * (2 * EDIM) + ecol + g * 8;
                uint4 pa = *(const uint4*)(xzp0 + o);
                uint4 pb = *(const uint4*)(xzp1 + o);
                const bf16* ba = (const bf16*)&pa;
                const bf16* bb = (const bf16*)&pb;
                bf16 t[8];
                #pragma unroll
                for (int q = 0; q < 8; q++) t[q] = (bf16)((float)ba[q] + (float)bb[q]);
                v = *(const uint4*)t;
            }
            *(uint4*)&Xr[r][g * 8] = v;
        }
        #pragma unroll
        for (int i = 0; i < 2; i++) {
            int id = tid + i * 256;
            int r = id >> 3, g = id & 7;
            if (col0 + r < 80) {
                ld8(&Ws[r][g * 8], W + (size_t)(col0 + r) * EDIM + ecol + g * 8);
            } else {
                uint4 z = {0, 0, 0, 0};
                *(uint4*)&Ws[r][g * 8] = z;
            }
        }
        __syncthreads();
        {
            const int e = tid & 63;
            const int rb = (tid >> 6) * 16;
            const float cw0 = cw[(ecol + e) * 4 + 0];
            const float cw1 = cw[(ecol + e) * 4 + 1];
            const float cw2 = cw[(ecol + e) * 4 + 2];
            const float cw3 = cw[(ecol + e) * 4 + 3];
            const float cbv = cb[ecol + e];
            #pragma unroll
            for (int j = 0; j < 16; j++) {
                int r = rb + j;
                float s = cbv
                        + cw0 * (float)Xr[r + 0][e]
                        + cw1 * (float)Xr[r + 1][e]
                        + cw2 * (float)Xr[r + 2][e]
                        + cw3 * (float)Xr[r + 3][e];
                bf16 h = (bf16)siluf(s);
                As[r][e] = *reinterpret_cast<short*>(&h);
            }
        }
        __syncthreads();
        if (blockIdx.x == 0) {
            for (int idx = tid; idx < 64 * 8; idx += 256) {
                int r = idx >> 3, g = idx & 7;
                *(uint4*)(ub + (size_t)(row0 + r) * EDIM + ecol + g * 8) = *(const uint4*)&As[r][g * 8];
            }
        }
        #pragma unroll
        for (int ks = 0; ks < 64; ks += 32) {
            short8 af[2], bfr[2];
            #pragma unroll
            for (int i = 0; i < 2; i++) af[i] = *(const short8*)&As[wm * 32 + i * 16 + l16][ks + quad * 8];
            #pragma unroll
            for (int j = 0; j < 2; j++) bfr[j] = *(const short8*)&Ws[wn * 32 + j * 16 + l16][ks + quad * 8];
            #pragma unroll
            for (int i = 0; i < 2; i++)
                #pragma unroll
                for (int j = 0; j < 2; j++)
                    acc[i][j] = __builtin_amdgcn_mfma_f32_16x16x32_bf16(af[i], bfr[j], acc[i][j], 0, 0, 0);
        }
        __syncthreads();
    }

    float* pdst = part + (size_t)blockIdx.z * (LSEQ * 80);
    #pragma unroll
    for (int i = 0; i < 2; i++) {
        #pragma unroll
        for (int j = 0; j < 2; j++) {
            int gn = col0 + wn * 32 + j * 16 + l16;
            int gm0 = row0 + wm * 32 + i * 16 + quad * 4;
            if (gn < 80) {
                #pragma unroll
                for (int r = 0; r < 4; r++)
                    pdst[(size_t)(gm0 + r) * 80 + gn] = acc[i][j][r];
            }
        }
    }
}

// ---------------- split-K reduce: part[XSPLIT][LSEQ][80] -> dbc[LSEQ][80] ------------
__global__ __launch_bounds__(256) void k_red8(const float* __restrict__ part,
                                              float* __restrict__ dbc)
{
    const int i = (blockIdx.x * 256 + threadIdx.x) * 4;
    float4 s = *(const float4*)(part + i);
    #pragma unroll
    for (int p = 1; p < XSPLIT; p++) {
        float4 v = *(const float4*)(part + (size_t)p * (LSEQ * 80) + i);
        s.x += v.x; s.y += v.y; s.z += v.z; s.w += v.w;
    }
    *(float4*)(dbc + i) = s;
}

// ---------------- residual + rmsnorm (sums HSPLIT=4 partials) ----------------
__global__ __launch_bounds__(256) void k_rms(const float* __restrict__ hp,
                                             float* __restrict__ res,
                                             bf16* __restrict__ hnb, const float* __restrict__ w,
                                             int first)
{
    __shared__ float red[4];
    __shared__ float tot;
    const int tid = threadIdx.x;
    const int t = blockIdx.x;
    const size_t LH = (size_t)LSEQ * HDIM;
    float v[3]; float ss = 0.f;
    #pragma unroll
    for (int r = 0; r < 3; r++) {
        int j = tid + r * 256;
        size_t o = (size_t)t * HDIM + j;
        float xv = hp[o] + hp[LH + o] + hp[2 * LH + o] + hp[3 * LH + o];
        if (!first) xv += res[o];
        v[r] = xv;
        res[o] = xv;
        ss += xv * xv;
    }
    #pragma unroll
    for (int m = 32; m >= 1; m >>= 1) ss += __shfl_down(ss, m);
    int wid = tid >> 6;
    if ((tid & 63) == 0) red[wid] = ss;
    __syncthreads();
    if (tid == 0) tot = red[0] + red[1] + red[2] + red[3];
    __syncthreads();
    float scale = rsqrtf(tot / (float)HDIM + 1e-5f);
    #pragma unroll
    for (int r = 0; r < 3; r++) {
        int j = tid + r * 256;
        hnb[(size_t)t * HDIM + j] = (bf16)(v[r] * scale * w[j]);
    }
}

// ---------------- shared helper: per-block dt/B/C tile from reduced dbc ----------
__device__ __forceinline__ void dt_tile(
    const float* __restrict__ dbc, const float* __restrict__ dtw,
    const float* __restrict__ dtbb,
    float (*A_red)[48], float (*BC)[32], float (*dtL)[256],
    int t0, int e, int tid)
{
    for (int idx = tid; idx < CHLEN * 80; idx += 256) {
        int tt = idx / 80, k = idx - tt * 80;
        float v = dbc[(size_t)(t0 + tt) * 80 + k];
        if (k < RDIM) A_red[tt][k] = v; else BC[tt][k - RDIM] = v;
    }
    __syncthreads();
    const float* we = dtw + (size_t)e * RDIM;
    const float bb = dtbb[e];
    float acc[CHLEN] = {};
    #pragma unroll 3
    for (int k = 0; k < RDIM; k += 4) {
        float4 w4 = *(const float4*)(we + k);
        #pragma unroll
        for (int j = 0; j < CHLEN; j++) {
            float4 a4 = *(const float4*)&A_red[j][k];
            acc[j] += a4.x * w4.x + a4.y * w4.y + a4.z * w4.z + a4.w * w4.w;
        }
    }
    #pragma unroll
    for (int j = 0; j < CHLEN; j++)
        dtL[j][tid] = softplusf(acc[j] + bb);
}

// ---------------- scan1: dt-GEMM + per-chunk local scan ----------------
__global__ __launch_bounds__(256) void k_scan1d(
    const float* __restrict__ dbc, const float* __restrict__ dtw,
    const float* __restrict__ dtbb,
    const bf16*  __restrict__ ub,
    const float* __restrict__ a_log,
    float* __restrict__ chunkS, float* __restrict__ sumdt)
{
    __shared__ __align__(16) float A_red[CHLEN][48];
    __shared__ __align__(16) float BC[CHLEN][32];
    __shared__ __align__(16) float dtL[CHLEN][256];
    const int tid = threadIdx.x;
    const int ex = blockIdx.x % 6, c = blockIdx.x / 6;
    const int e = ex * 256 + tid;
    const int t0 = c * CHLEN;

    dt_tile(dbc, dtw, dtbb, A_red, BC, dtL, t0, e, tid);

    // prefetch u for the whole chunk (independent loads, batched issue)
    float u8[CHLEN];
    #pragma unroll
    for (int tt = 0; tt < CHLEN; tt++)
        u8[tt] = (float)ub[(size_t)(t0 + tt) * EDIM + e];

    float A[16];
    #pragma unroll
    for (int q = 0; q < 4; q++) {
        float4 a4 = *(const float4*)(a_log + (size_t)e * NDIM + q * 4);
        A[q*4+0] = -__expf(a4.x); A[q*4+1] = -__expf(a4.y);
        A[q*4+2] = -__expf(a4.z); A[q*4+3] = -__expf(a4.w);
    }
    float s[16] = {};
    float sd = 0.f;
    #pragma unroll
    for (int tt = 0; tt < CHLEN; tt++) {
        float dtv = dtL[tt][tid];
        float dtu = dtv * u8[tt];
        sd += dtv;
        #pragma unroll
        for (int n = 0; n < 16; n++) s[n] = s[n] * __expf(dtv * A[n]) + dtu * BC[tt][n];
    }
    float* cs = chunkS + ((size_t)c * EDIM + e) * NDIM;
    #pragma unroll
    for (int q = 0; q < 4; q++)
        *(float4*)(cs + q * 4) = make_float4(s[q*4+0], s[q*4+1], s[q*4+2], s[q*4+3]);
    sumdt[(size_t)c * EDIM + e] = sd;
}

// ---------------- scan2: two-level affine prefix over chunks -> sInit ----------------
__global__ __launch_bounds__(256) void k_scan2p(
    const float* __restrict__ chunkS, const float* __restrict__ sumdt,
    const float* __restrict__ a_log, float* __restrict__ sInit)
{
    __shared__ float sP[256];
    __shared__ float sX[256];
    const int tid = threadIdx.x;
    const int pl = tid & 63, q = tid >> 6;
    const int p = blockIdx.x * 64 + pl;   // pair index = e*16+n
    const int pe = p >> 4;
    const float Aen = -__expf(a_log[p]);
    float P[CPG], X[CPG];
    float Pc = 1.f, Xc = 0.f;
    #pragma unroll
    for (int j = 0; j < CPG; j++) {
        int cc = q * CPG + j;
        float Pj = __expf(Aen * sumdt[(size_t)cc * EDIM + pe]);
        float Xj = chunkS[(size_t)cc * (EDIM * NDIM) + p];
        P[j] = Pj; X[j] = Xj;
        Xc = Pj * Xc + Xj;
        Pc *= Pj;
    }
    sP[q * 64 + pl] = Pc;
    sX[q * 64 + pl] = Xc;
    __syncthreads();
    float s = 0.f;
    for (int g = 0; g < q; g++) s = sP[g * 64 + pl] * s + sX[g * 64 + pl];
    #pragma unroll
    for (int j = 0; j < CPG; j++) {
        int cc = q * CPG + j;
        sInit[(size_t)cc * (EDIM * NDIM) + p] = s;
        s = P[j] * s + X[j];
    }
}

// ---------------- scan3: dt-GEMM + final scan with carry + y/z gating ----------
__global__ __launch_bounds__(256) void k_scan3d(
    const float* __restrict__ dbc, const float* __restrict__ dtw,
    const float* __restrict__ dtbb,
    const bf16*  __restrict__ ub,
    const bf16*  __restrict__ xzp0,
    const bf16*  __restrict__ xzp1,
    const float* __restrict__ a_log,
    const float* __restrict__ Dp,
    const float* __restrict__ sInit,
    bf16* __restrict__ yzb)
{
    __shared__ __align__(16) float A_red[CHLEN][48];
    __shared__ __align__(16) float BC[CHLEN][32];
    __shared__ __align__(16) float dtL[CHLEN][256];
    const int tid = threadIdx.x;
    const int ex = blockIdx.x % 6, c = blockIdx.x / 6;
    const int e = ex * 256 + tid;
    const int t0 = c * CHLEN;

    dt_tile(dbc, dtw, dtbb, A_red, BC, dtL, t0, e, tid);

    // prefetch u and z for the whole chunk (z = p0+p1, fp32 add; round-0 path)
    float u8[CHLEN], z8[CHLEN];
    #pragma unroll
    for (int tt = 0; tt < CHLEN; tt++) {
        u8[tt] = (float)ub[(size_t)(t0 + tt) * EDIM + e];
        size_t zo = (size_t)(t0 + tt) * (2 * EDIM) + EDIM + e;
        z8[tt] = (float)xzp0[zo] + (float)xzp1[zo];
    }

    float A[16];
    #pragma unroll
    for (int q = 0; q < 4; q++) {
        float4 a4 = *(const float4*)(a_log + (size_t)e * NDIM + q * 4);
        A[q*4+0] = -__expf(a4.x); A[q*4+1] = -__expf(a4.y);
        A[q*4+2] = -__expf(a4.z); A[q*4+3] = -__expf(a4.w);
    }
    const float dv = Dp[e];
    float s[16];
    const float* si = sInit + ((size_t)c * EDIM + e) * NDIM;
    #pragma unroll
    for (int q = 0; q < 4; q++) {
        float4 s4 = *(const float4*)(si + q * 4);
        s[q*4+0] = s4.x; s[q*4+1] = s4.y; s[q*4+2] = s4.z; s[q*4+3] = s4.w;
    }
    #pragma unroll
    for (int tt = 0; tt < CHLEN; tt++) {
        float dtv = dtL[tt][tid];
        float uv  = u8[tt];
        float dtu = dtv * uv;
        float y = 0.f;
        #pragma unroll
        for (int n = 0; n < 16; n++) {
            s[n] = s[n] * __expf(dtv * A[n]) + dtu * BC[tt][n];
            y += s[n] * BC[tt][16 + n];
        }
        y += uv * dv;
        yzb[(size_t)(t0 + tt) * EDIM + e] = (bf16)(y * siluf(z8[tt]));
    }
}

extern "C" void kernel_launch(void* const* d_in, const int* in_sizes, int n_in,
                              void* d_out, int out_size, void* d_ws, size_t ws_size,
                              hipStream_t stream)
{
    const float* x        = (const float*)d_in[0];
    const float* emb_w    = (const float*)d_in[1];
    const float* emb_b    = (const float*)d_in[2];
    const float* norm_w   = (const float*)d_in[3];
    const float* in_proj  = (const float*)d_in[4];
    const float* conv_w   = (const float*)d_in[5];
    const float* conv_b   = (const float*)d_in[6];
    const float* x_proj   = (const float*)d_in[7];
    const float* dt_w     = (const float*)d_in[8];
    const float* dt_b     = (const float*)d_in[9];
    const float* A_log    = (const float*)d_in[10];
    const float* Dp       = (const float*)d_in[11];
    const float* out_proj = (const float*)d_in[12];
    const float* head_w   = (const float*)d_in[13];
    const float* head_b   = (const float*)d_in[14];
    float* out = (float*)d_out;

    float* ws = (float*)d_ws;
    size_t off = 0;
    float* hpart  = ws + off; off += (size_t)HSPLIT * LSEQ * HDIM;
    float* res    = ws + off; off += (size_t)LSEQ * HDIM;
    float* part   = ws + off; off += (size_t)XSPLIT * LSEQ * 80;
    float* dbc    = ws + off; off += (size_t)LSEQ * 80;
    float* chunkS = ws + off; off += (size_t)NCHUNK * EDIM * NDIM;
    float* sumdt  = ws + off; off += (size_t)NCHUNK * EDIM;
    float* sInit  = ws + off; off += (size_t)NCHUNK * EDIM * NDIM;
    bf16* xzpart  = (bf16*)(ws + off); off += (size_t)ISPLIT * LSEQ * 2 * EDIM / 2;
    bf16* hnb     = (bf16*)(ws + off); off += (size_t)LSEQ * HDIM / 2;
    bf16* yzb     = (bf16*)(ws + off); off += (size_t)LSEQ * EDIM / 2;
    bf16* ub      = (bf16*)(ws + off); off += (size_t)LSEQ * EDIM / 2;

    // embed: split-K=4 (Kh=64) -> hpart[4]; 768 blocks (3/CU)
    k_gemm_sk<float><<<dim3(12, 16, HSPLIT), 256, 0, stream>>>(x, SDIM, emb_w, SDIM, emb_b,
                                                               hpart, HDIM, SDIM / HSPLIT, 1);

    for (int l = 0; l < NLAYER; l++) {
        const float* inw  = in_proj  + (size_t)l * 2 * EDIM * HDIM;
        const float* outw = out_proj + (size_t)l * HDIM * EDIM;
        const float* xwl  = x_proj   + (size_t)l * 80 * EDIM;
        const float* cw   = conv_w   + (size_t)l * EDIM * KCONV;
        const float* cb   = conv_b   + (size_t)l * EDIM;
        const float* dtw  = dt_w     + (size_t)l * EDIM * RDIM;
        const float* dtbb = dt_b     + (size_t)l * EDIM;
        const float* al   = A_log    + (size_t)l * EDIM * NDIM;
        const float* Dpl  = Dp       + (size_t)l * EDIM;

        k_rms<<<LSEQ, 256, 0, stream>>>(hpart, res, hnb, norm_w + (size_t)l * HDIM, l == 0);
        // in_proj: split-K=2 (Kh=384) -> bf16 partials; 1536 blocks (6/CU)
        k_gemm_skb<<<dim3(48, 16, ISPLIT), 256, 0, stream>>>(hnb, HDIM, inw, HDIM,
                                                             xzpart, 2 * EDIM, HDIM / ISPLIT);
        // xproj with fused conv+silu; XSPLIT=24 -> 768 blocks (3/CU)
        k_xproj_conv<<<dim3(2, 16, XSPLIT), 256, 0, stream>>>(
            xzpart, xzpart + (size_t)LSEQ * 2 * EDIM, xwl, cw, cb, part, ub);
        // dedicated split-K reduce (coalesced), then 3 scan kernels read dbc
        k_red8<<<LSEQ * 80 / 1024, 256, 0, stream>>>(part, dbc);
        k_scan1d<<<6 * NCHUNK, 256, 0, stream>>>(dbc, dtw, dtbb, ub, al, chunkS, sumdt);
        k_scan2p<<<EDIM * NDIM / 64, 256, 0, stream>>>(chunkS, sumdt, al, sInit);
        k_scan3d<<<6 * NCHUNK, 256, 0, stream>>>(dbc, dtw, dtbb, ub,
                                                 xzpart, xzpart + (size_t)LSEQ * 2 * EDIM,
                                                 al, Dpl, sInit, yzb);
        // out_proj: split-K=4 (Kh=384) -> hpart[4]; 768 blocks (3/CU)
        k_gemm_sk<bf16><<<dim3(12, 16, HSPLIT), 256, 0, stream>>>(yzb, EDIM, outw, EDIM, nullptr,
                                                                  hpart, HDIM, EDIM / HSPLIT, 0);
    }

    // head: A = sum of 4 fp32 partials, W fp32 converted in staging
    k_gemm_h<<<dim3(4, 16), 256, 0, stream>>>(hpart, HDIM, head_w, HDIM, head_b,
                                              out, SDIM, HDIM);
}